// Round 9
// baseline (303.046 us; speedup 1.0000x reference)
//
#include <hip/hip_runtime.h>
#include <math.h>

#define NB 8
#define NA 512
#define NN 64
#define ND 128
#define NF 128
#define NG 25
#define NGA 512

typedef __attribute__((ext_vector_type(8))) short bf16x8;
typedef __attribute__((ext_vector_type(4))) float f32x4;

__device__ __forceinline__ float sspf(float v) {
  return fmaxf(v, 0.0f) + __logf(1.0f + __expf(-fabsf(v))) - 0.6931471805599453f;
}

__device__ __forceinline__ short f2bf(float x) {
  union { float f; unsigned u; } v; v.f = x;
  unsigned r = v.u + 0x7fffu + ((v.u >> 16) & 1u);   // RNE
  return (short)(r >> 16);
}

__device__ __forceinline__ unsigned pk2bf(float a, float b) {
  union { float f; unsigned u; } x, y; x.f = a; y.f = b;
  const unsigned ra = (x.u + 0x7fffu + ((x.u >> 16) & 1u)) >> 16;
  const unsigned rb = (y.u + 0x7fffu + ((y.u >> 16) & 1u)) & 0xffff0000u;
  return ra | rb;
}

__device__ __forceinline__ float bf2f(unsigned short us) {
  union { unsigned u; float f; } v; v.u = ((unsigned)us) << 16; return v.f;
}

__device__ __forceinline__ bf16x8 pack8(float4 a, float4 b) {
  bf16x8 r;
  r[0] = f2bf(a.x); r[1] = f2bf(a.y); r[2] = f2bf(a.z); r[3] = f2bf(a.w);
  r[4] = f2bf(b.x); r[5] = f2bf(b.y); r[6] = f2bf(b.z); r[7] = f2bf(b.w);
  return r;
}

#define NW1 (3 * 128 * 32)      // 12288
#define NSQ (3 * 128 * 128)     // 49152
#define NAW (3 * 128 * 512)     // 196608
#define PW_BLK ((NW1 + 2 * NSQ + NAW) / 256)   // 1200
#define PF_BLK 24
#define PE_BLK 7

// ================= prep A: weights bf16-T, W12 fuse, embY ==================
__global__ __launch_bounds__(256) void k_prepA(
    const float* __restrict__ fw1, const float* __restrict__ fw2,
    const float* __restrict__ in2f, const float* __restrict__ aw,
    const float* __restrict__ f2o, const float* __restrict__ f2ob,
    const float* __restrict__ dw, const float* __restrict__ db,
    const float* __restrict__ emb,
    short* __restrict__ w1T, short* __restrict__ w2T,
    short* __restrict__ in2fT, short* __restrict__ awT,
    short* __restrict__ W12T, float* __restrict__ b12,
    short* __restrict__ embYB) {
  const int bx = blockIdx.x;
  const int t = threadIdx.x;
  if (bx < PW_BLK) {
    int idx = bx * 256 + t;
    if (idx < NW1) {
      const int l = idx >> 12, r = idx & 4095, n = r >> 5, k = r & 31;
      w1T[idx] = (k < NG) ? f2bf(fw1[(size_t)l * NG * NF + k * NF + n]) : (short)0;
      return;
    }
    idx -= NW1;
    if (idx < 2 * NSQ) {
      const int which = idx / NSQ, q = idx % NSQ;
      const int l = q >> 14, r = q & 16383, n = r >> 7, k = r & 127;
      const float* src = (which == 0) ? fw2 : in2f;
      short* dst = (which == 0) ? w2T : in2fT;
      dst[q] = f2bf(src[(size_t)l * 16384 + k * 128 + n]);
      return;
    }
    idx -= 2 * NSQ;
    if (idx < NAW) {
      const int l = idx >> 16, r = idx & 65535, n = r >> 9, k = r & 511;
      awT[idx] = f2bf(aw[(size_t)l * 65536 + k * 128 + n]);
    }
    return;
  }
  const int lane = t & 63, wave = t >> 6;
  const int lanelo = lane & 15, quad = lane >> 4;
  const int wbase = wave << 5;
  if (bx < PW_BLK + PF_BLK) {
    // ---- W12 = f2o@dw (bf16), b12 = f2ob@dw + db ----
    const int fb = bx - PW_BLK;
    const int l = fb >> 3, xi = fb & 7;
    const int i = (xi << 4) + lanelo;
    const float* f2o_l = f2o + (size_t)l * 16384;
    const float* dw_l = dw + (size_t)l * 16384;
    short* W12T_l = W12T + (size_t)l * 16384;
    f32x4 c[2] = {{0.f, 0.f, 0.f, 0.f}, {0.f, 0.f, 0.f, 0.f}};
#pragma unroll
    for (int kt = 0; kt < 4; ++kt) {
      const int k0 = kt * 32 + quad * 8;
      const bf16x8 b = pack8(*(const float4*)(f2o_l + (size_t)i * 128 + k0),
                             *(const float4*)(f2o_l + (size_t)i * 128 + k0 + 4));
#pragma unroll
      for (int ct = 0; ct < 2; ++ct) {
        const int j = wbase + ct * 16 + lanelo;
        bf16x8 a;
#pragma unroll
        for (int q = 0; q < 8; ++q) a[q] = f2bf(dw_l[(size_t)(k0 + q) * 128 + j]);
        c[ct] = __builtin_amdgcn_mfma_f32_16x16x32_bf16(a, b, c[ct], 0, 0, 0);
      }
    }
#pragma unroll
    for (int ct = 0; ct < 2; ++ct)
#pragma unroll
      for (int reg = 0; reg < 4; ++reg) {
        const int j = wbase + ct * 16 + quad * 4 + reg;
        W12T_l[(size_t)j * 128 + i] = f2bf(c[ct][reg]);
      }
    if (xi == 0 && t < 128) {
      float acc = db[(size_t)l * 128 + t];
      for (int k = 0; k < 128; ++k)
        acc += f2ob[(size_t)l * 128 + k] * dw_l[(size_t)k * 128 + t];
      b12[(size_t)l * 128 + t] = acc;
    }
    return;
  }
  // ---- embY = emb @ in2f[0] -> bf16 ----
  const int z = ((bx - PW_BLK - PF_BLK) << 4) + lanelo;
  const int zc = (z < 100) ? z : 99;
  f32x4 c[2] = {{0.f, 0.f, 0.f, 0.f}, {0.f, 0.f, 0.f, 0.f}};
#pragma unroll
  for (int kt = 0; kt < 4; ++kt) {
    const int k0 = kt * 32 + quad * 8;
    const bf16x8 b = pack8(*(const float4*)(emb + (size_t)zc * 128 + k0),
                           *(const float4*)(emb + (size_t)zc * 128 + k0 + 4));
#pragma unroll
    for (int ct = 0; ct < 2; ++ct) {
      const bf16x8 a = *(const bf16x8*)(in2fT + (wbase + ct * 16 + lanelo) * 128 + k0);
      c[ct] = __builtin_amdgcn_mfma_f32_16x16x32_bf16(a, b, c[ct], 0, 0, 0);
    }
  }
  if (z < 100) {
#pragma unroll
    for (int ct = 0; ct < 2; ++ct) {
      const int c0 = wbase + ct * 16 + quad * 4;
      uint2 pk; pk.x = pk2bf(c[ct][0], c[ct][1]); pk.y = pk2bf(c[ct][2], c[ct][3]);
      *(uint2*)(embYB + (size_t)z * 128 + c0) = pk;
    }
  }
}

// ================= prep B: vang GEMM + init gather =========================
__global__ __launch_bounds__(256) void k_prepB(
    const float* __restrict__ Gi, const short* __restrict__ awT,
    const int* __restrict__ zn, const float* __restrict__ emb,
    const short* __restrict__ embYB,
    float* __restrict__ vang, float* __restrict__ x, short* __restrict__ yB) {
  const int bx = blockIdx.x;
  const int t = threadIdx.x;
  if (bx < 768) {
    const int lane = t & 63, wave = t >> 6;
    const int lanelo = lane & 15, quad = lane >> 4;
    const int wbase = wave << 5;
    const int l = bx >> 8;
    const int row = ((bx & 255) << 4) + lanelo;
    const short* aw = awT + (size_t)l * 128 * NGA;
    f32x4 c[2] = {{0.f, 0.f, 0.f, 0.f}, {0.f, 0.f, 0.f, 0.f}};
#pragma unroll
    for (int kt = 0; kt < 16; ++kt) {
      const int k0 = kt * 32 + quad * 8;
      const bf16x8 b = pack8(*(const float4*)(Gi + (size_t)row * NGA + k0),
                             *(const float4*)(Gi + (size_t)row * NGA + k0 + 4));
#pragma unroll
      for (int ct = 0; ct < 2; ++ct) {
        const bf16x8 a = *(const bf16x8*)(aw + (size_t)(wbase + ct * 16 + lanelo) * NGA + k0);
        c[ct] = __builtin_amdgcn_mfma_f32_16x16x32_bf16(a, b, c[ct], 0, 0, 0);
      }
    }
    float* vrow = vang + ((size_t)l * NB * NA + row) * 128;
#pragma unroll
    for (int ct = 0; ct < 2; ++ct) {
      float4 o = make_float4(c[ct][0], c[ct][1], c[ct][2], c[ct][3]);
      *(float4*)(vrow + wbase + ct * 16 + quad * 4) = o;
    }
    return;
  }
  const int ga = (bx - 768) * 2 + (t >> 7);
  const int tt = t & 127;
  const int z = zn[ga];
  x[(size_t)ga * 128 + tt] = emb[(size_t)z * 128 + tt];
  yB[(size_t)ga * 128 + tt] = embYB[(size_t)z * 128 + tt];
}

// ================= fused layer: CFConv (2 atoms) + update tail =============
// 256 thr = 4 waves. CFConv per atom: phase1 wave w owns j-tile w (all 128 f,
// gauss frag stays in-register); phase2 wave w owns f-cols [w*32,+32).
// Tail: 2-row update GEMMs (rows = lanelo<2) using LDS agg.
#define HPAD 136
__global__ __launch_bounds__(256) void k_layer(
    const float* __restrict__ pos, const int* __restrict__ nbr,
    const int* __restrict__ nmask, const short* __restrict__ yBin,
    const short* __restrict__ w1T, const float* __restrict__ b1,
    const short* __restrict__ w2T, const float* __restrict__ b2,
    float* __restrict__ x, const float* __restrict__ vangl,
    const short* __restrict__ W12Tl, const float* __restrict__ b12l,
    const short* __restrict__ in2fTn, short* __restrict__ yBout) {
  __shared__ alignas(16) short sH[NN * HPAD];   // h tile; aliased as sPart
  __shared__ alignas(16) float sAgg[2 * NF];    // per-atom agg rows (fp32)
  __shared__ alignas(16) short sXn[2 * NF];     // x_new bf16 rows for GEMM_B
  __shared__ float sR[NN];
  __shared__ float sScale[NN];
  __shared__ int sNbr[NN];

  const int t = threadIdx.x;
  const int ga0 = blockIdx.x * 2;
  const int b0 = ga0 & ~(NA - 1);
  const int lane = t & 63;
  const int wave = t >> 6;
  const int lanelo = lane & 15;
  const int quad = lane >> 4;
  const int wbase = wave << 5;

  // phase-2 weight fragments: persistent per block
  bf16x8 bw2[8];
#pragma unroll
  for (int ct = 0; ct < 2; ++ct) {
    const int n = wbase + ct * 16 + lanelo;
#pragma unroll
    for (int kt = 0; kt < 4; ++kt)
      bw2[ct * 4 + kt] = *(const bf16x8*)(w2T + n * 128 + kt * 32 + quad * 8);
  }
  float b2r[2];
#pragma unroll
  for (int ct = 0; ct < 2; ++ct) b2r[ct] = b2[wbase + ct * 16 + lanelo];

  const float step = 3.8f / 24.0f;
  const float coef = -0.5f / (step * step);

  for (int a = 0; a < 2; ++a) {
    const int ga = ga0 + a;
    if (t < NN) {
      const int nj = nbr[(size_t)ga * NN + t];
      sNbr[t] = nj;
      const float px = pos[(size_t)ga * 3];
      const float py = pos[(size_t)ga * 3 + 1];
      const float pz = pos[(size_t)ga * 3 + 2];
      const float* pj = pos + (size_t)(b0 + nj) * 3;
      const float dx = pj[0] - px, dy = pj[1] - py, dz = pj[2] - pz;
      const float r = sqrtf(dx * dx + dy * dy + dz * dz + 1e-12f);
      sR[t] = r;
      sScale[t] = (r <= 5.0f && nmask[(size_t)ga * NN + t] != 0) ? 1.0f : 0.0f;
    }
    __syncthreads();   // sR ready; prev atom's sPart reads done -> sH reusable

    // ---- phase 1: wave w handles j = w*16+lanelo over all 128 f ----
    {
      const int j = wave * 16 + lanelo;
      const float r = sR[j];
      bf16x8 gb;
#pragma unroll
      for (int i = 0; i < 8; ++i) {
        const int g = quad * 8 + i;
        const float d = r - (1.2f + step * (float)g);
        gb[i] = (g < NG) ? f2bf(__expf(coef * d * d)) : (short)0;
      }
#pragma unroll
      for (int ct = 0; ct < 8; ++ct) {
        const bf16x8 aw1 = *(const bf16x8*)(w1T + (ct * 16 + lanelo) * 32 + quad * 8);
        f32x4 c = {0.f, 0.f, 0.f, 0.f};
        c = __builtin_amdgcn_mfma_f32_16x16x32_bf16(aw1, gb, c, 0, 0, 0);
        // C: col(lanelo)=j-local, row(quad*4+reg)=f-local -> f = ct*16+quad*4+reg
        const int f0 = ct * 16 + quad * 4;
        const float4 bv = *(const float4*)(b1 + f0);
        uint2 pk;
        pk.x = pk2bf(sspf(c[0] + bv.x), sspf(c[1] + bv.y));
        pk.y = pk2bf(sspf(c[2] + bv.z), sspf(c[3] + bv.w));
        *(uint2*)(sH + j * HPAD + f0) = pk;
      }
    }
    __syncthreads();

    // ---- phase 2: W = h @ w2 (+b2); consume against global bf16 y ----
    float pagg[2] = {0.f, 0.f};
#pragma unroll
    for (int rt = 0; rt < 4; ++rt) {
      f32x4 acc[2];
      acc[0] = (f32x4){b2r[0], b2r[0], b2r[0], b2r[0]};
      acc[1] = (f32x4){b2r[1], b2r[1], b2r[1], b2r[1]};
#pragma unroll
      for (int kt = 0; kt < 4; ++kt) {
        const bf16x8 ah = *(const bf16x8*)(sH + (rt * 16 + lanelo) * HPAD + kt * 32 + quad * 8);
#pragma unroll
        for (int ct = 0; ct < 2; ++ct)
          acc[ct] = __builtin_amdgcn_mfma_f32_16x16x32_bf16(ah, bw2[ct * 4 + kt], acc[ct], 0, 0, 0);
      }
#pragma unroll
      for (int reg = 0; reg < 4; ++reg) {
        const int j = rt * 16 + quad * 4 + reg;
        const float sc = sScale[j];
        const unsigned short* yr =
            (const unsigned short*)(yBin + (size_t)(b0 + sNbr[j]) * NF) + wbase + lanelo;
#pragma unroll
        for (int ct = 0; ct < 2; ++ct)
          pagg[ct] = fmaf(sc * acc[ct][reg], bf2f(yr[ct * 16]), pagg[ct]);
      }
    }

    __syncthreads();               // sH reads done -> alias as sPart
    float* sPart = (float*)sH;
#pragma unroll
    for (int ct = 0; ct < 2; ++ct)
      sPart[quad * NF + wbase + ct * 16 + lanelo] = pagg[ct];
    __syncthreads();
    if (t < NF)
      sAgg[a * NF + t] = sPart[t] + sPart[NF + t] + sPart[2 * NF + t] + sPart[3 * NF + t];
  }
  __syncthreads();   // sAgg complete

  // ================= update tail: rows = ga0 + lanelo (lanelo<2) ===========
  // GEMM_A: v = agg @ W12T
  f32x4 c2[2] = {{0.f, 0.f, 0.f, 0.f}, {0.f, 0.f, 0.f, 0.f}};
#pragma unroll
  for (int kt = 0; kt < 4; ++kt) {
    bf16x8 b = {0, 0, 0, 0, 0, 0, 0, 0};
    if (lanelo < 2) {
      const float* ap = sAgg + lanelo * NF + kt * 32 + quad * 8;
      b = pack8(*(const float4*)ap, *(const float4*)(ap + 4));
    }
#pragma unroll
    for (int ct = 0; ct < 2; ++ct) {
      const bf16x8 aw = *(const bf16x8*)(W12Tl + (wbase + ct * 16 + lanelo) * 128 + kt * 32 + quad * 8);
      c2[ct] = __builtin_amdgcn_mfma_f32_16x16x32_bf16(aw, b, c2[ct], 0, 0, 0);
    }
  }
  // epilogue: x += ssp(v + b12 + vang); stage x_new bf16
  if (lanelo < 2) {
    const int row = ga0 + lanelo;
#pragma unroll
    for (int ct = 0; ct < 2; ++ct) {
      const int c0 = wbase + ct * 16 + quad * 4;
      const float4 dv = *(const float4*)(b12l + c0);
      const float4 vv = *(const float4*)(vangl + (size_t)row * 128 + c0);
      float* xp = x + (size_t)row * 128 + c0;
      const float4 xv = *(const float4*)xp;
      float4 xo;
      xo.x = xv.x + sspf(c2[ct][0] + vv.x + dv.x);
      xo.y = xv.y + sspf(c2[ct][1] + vv.y + dv.y);
      xo.z = xv.z + sspf(c2[ct][2] + vv.z + dv.z);
      xo.w = xv.w + sspf(c2[ct][3] + vv.w + dv.w);
      *(float4*)xp = xo;
      if (in2fTn != nullptr) {
        uint2 pk; pk.x = pk2bf(xo.x, xo.y); pk.y = pk2bf(xo.z, xo.w);
        *(uint2*)(sXn + lanelo * NF + c0) = pk;
      }
    }
  }
  if (in2fTn == nullptr) return;
  __syncthreads();

  // GEMM_B: yBout = x_new @ in2fT
  f32x4 c3[2] = {{0.f, 0.f, 0.f, 0.f}, {0.f, 0.f, 0.f, 0.f}};
#pragma unroll
  for (int kt = 0; kt < 4; ++kt) {
    bf16x8 b = {0, 0, 0, 0, 0, 0, 0, 0};
    if (lanelo < 2)
      b = *(const bf16x8*)(sXn + lanelo * NF + kt * 32 + quad * 8);
#pragma unroll
    for (int ct = 0; ct < 2; ++ct) {
      const bf16x8 aw = *(const bf16x8*)(in2fTn + (wbase + ct * 16 + lanelo) * 128 + kt * 32 + quad * 8);
      c3[ct] = __builtin_amdgcn_mfma_f32_16x16x32_bf16(aw, b, c3[ct], 0, 0, 0);
    }
  }
  if (lanelo < 2) {
    const int row = ga0 + lanelo;
#pragma unroll
    for (int ct = 0; ct < 2; ++ct) {
      const int c0 = wbase + ct * 16 + quad * 4;
      uint2 pk; pk.x = pk2bf(c3[ct][0], c3[ct][1]); pk.y = pk2bf(c3[ct][2], c3[ct][3]);
      *(uint2*)(yBout + (size_t)row * 128 + c0) = pk;
    }
  }
}

extern "C" void kernel_launch(void* const* d_in, const int* in_sizes, int n_in,
                              void* d_out, int out_size, void* d_ws, size_t ws_size,
                              hipStream_t stream) {
  (void)in_sizes; (void)n_in; (void)out_size; (void)ws_size;
  const int* zn = (const int*)d_in[0];
  const float* pos = (const float*)d_in[1];
  const int* nbr = (const int*)d_in[2];
  const int* nmask = (const int*)d_in[3];
  const float* Gi = (const float*)d_in[4];
  const float* emb = (const float*)d_in[5];
  const float* fw1 = (const float*)d_in[6];
  const float* fb1 = (const float*)d_in[7];
  const float* fw2 = (const float*)d_in[8];
  const float* fb2 = (const float*)d_in[9];
  const float* in2f = (const float*)d_in[10];
  const float* f2o = (const float*)d_in[11];
  const float* f2ob = (const float*)d_in[12];
  const float* dwp = (const float*)d_in[13];
  const float* dbp = (const float*)d_in[14];
  const float* awp = (const float*)d_in[15];

  float* x = (float*)d_out;                            // [B,A,D] fp32
  float* vang = (float*)d_ws;                          // [3][B*A][128] fp32
  float* b12 = vang + (size_t)3 * NB * NA * ND;        // [3][128] fp32
  short* yA = (short*)(b12 + 3 * 128);                 // [B,A,F] bf16 (ping)
  short* yBb = yA + (size_t)NB * NA * NF;              // [B,A,F] bf16 (pong)
  short* w1T = yBb + (size_t)NB * NA * NF;             // [3][128][32]
  short* w2T = w1T + NW1;                              // [3][128][128]
  short* in2fT = w2T + NSQ;                            // [3][128][128]
  short* awT = in2fT + NSQ;                            // [3][128][512]
  short* W12T = awT + NAW;                             // [3][128][128]
  short* embYB = W12T + NSQ;                           // [112][128]

  k_prepA<<<PW_BLK + PF_BLK + PE_BLK, 256, 0, stream>>>(
      fw1, fw2, in2f, awp, f2o, f2ob, dwp, dbp, emb,
      w1T, w2T, in2fT, awT, W12T, b12, embYB);
  k_prepB<<<768 + NB * NA / 2, 256, 0, stream>>>(
      Gi, awT, zn, emb, embYB, vang, x, yA);
  for (int l = 0; l < 3; ++l) {
    short* yin = (l & 1) ? yBb : yA;
    short* yout = (l & 1) ? yA : yBb;
    k_layer<<<NB * NA / 2, 256, 0, stream>>>(pos, nbr, nmask, yin,
        w1T + (size_t)l * 128 * 32, fb1 + (size_t)l * NF,
        w2T + (size_t)l * 128 * 128, fb2 + (size_t)l * NF,
        x, vang + (size_t)l * NB * NA * ND,
        W12T + (size_t)l * 16384, b12 + (size_t)l * 128,
        (l < 2) ? (in2fT + (size_t)(l + 1) * 16384) : nullptr, yout);
  }
}

// Round 10
// 264.117 us; speedup vs baseline: 1.1474x; 1.1474x over previous
//
#include <hip/hip_runtime.h>
#include <math.h>

#define NB 8
#define NA 512
#define NN 64
#define ND 128
#define NF 128
#define NG 25
#define NGA 512

typedef __attribute__((ext_vector_type(8))) short bf16x8;
typedef __attribute__((ext_vector_type(4))) float f32x4;

__device__ __forceinline__ float sspf(float v) {
  return fmaxf(v, 0.0f) + __logf(1.0f + __expf(-fabsf(v))) - 0.6931471805599453f;
}

__device__ __forceinline__ short f2bf(float x) {
  union { float f; unsigned u; } v; v.f = x;
  unsigned r = v.u + 0x7fffu + ((v.u >> 16) & 1u);   // RNE
  return (short)(r >> 16);
}

__device__ __forceinline__ unsigned pk2bf(float a, float b) {
  union { float f; unsigned u; } x, y; x.f = a; y.f = b;
  const unsigned ra = (x.u + 0x7fffu + ((x.u >> 16) & 1u)) >> 16;
  const unsigned rb = (y.u + 0x7fffu + ((y.u >> 16) & 1u)) & 0xffff0000u;
  return ra | rb;
}

__device__ __forceinline__ float bf2f(unsigned short us) {
  union { unsigned u; float f; } v; v.u = ((unsigned)us) << 16; return v.f;
}

__device__ __forceinline__ bf16x8 pack8(float4 a, float4 b) {
  bf16x8 r;
  r[0] = f2bf(a.x); r[1] = f2bf(a.y); r[2] = f2bf(a.z); r[3] = f2bf(a.w);
  r[4] = f2bf(b.x); r[5] = f2bf(b.y); r[6] = f2bf(b.z); r[7] = f2bf(b.w);
  return r;
}

#define NW1 (3 * 128 * 32)      // 12288
#define NSQ (3 * 128 * 128)     // 49152
#define NAW (3 * 128 * 512)     // 196608
#define PW_BLK ((NW1 + 2 * NSQ + NAW) / 256)   // 1200
#define PF_BLK 24
#define PE_BLK 7

// ================= prep A: weights bf16-T, W12 fuse, embY ==================
__global__ __launch_bounds__(256) void k_prepA(
    const float* __restrict__ fw1, const float* __restrict__ fw2,
    const float* __restrict__ in2f, const float* __restrict__ aw,
    const float* __restrict__ f2o, const float* __restrict__ f2ob,
    const float* __restrict__ dw, const float* __restrict__ db,
    const float* __restrict__ emb,
    short* __restrict__ w1T, short* __restrict__ w2T,
    short* __restrict__ in2fT, short* __restrict__ awT,
    short* __restrict__ W12T, float* __restrict__ b12,
    short* __restrict__ embYB) {
  const int bx = blockIdx.x;
  const int t = threadIdx.x;
  if (bx < PW_BLK) {
    int idx = bx * 256 + t;
    if (idx < NW1) {
      const int l = idx >> 12, r = idx & 4095, n = r >> 5, k = r & 31;
      w1T[idx] = (k < NG) ? f2bf(fw1[(size_t)l * NG * NF + k * NF + n]) : (short)0;
      return;
    }
    idx -= NW1;
    if (idx < 2 * NSQ) {
      const int which = idx / NSQ, q = idx % NSQ;
      const int l = q >> 14, r = q & 16383, n = r >> 7, k = r & 127;
      const float* src = (which == 0) ? fw2 : in2f;
      short* dst = (which == 0) ? w2T : in2fT;
      dst[q] = f2bf(src[(size_t)l * 16384 + k * 128 + n]);
      return;
    }
    idx -= 2 * NSQ;
    if (idx < NAW) {
      const int l = idx >> 16, r = idx & 65535, n = r >> 9, k = r & 511;
      awT[idx] = f2bf(aw[(size_t)l * 65536 + k * 128 + n]);
    }
    return;
  }
  const int lane = t & 63, wave = t >> 6;
  const int lanelo = lane & 15, quad = lane >> 4;
  const int wbase = wave << 5;
  if (bx < PW_BLK + PF_BLK) {
    // ---- W12 = f2o@dw (bf16), b12 = f2ob@dw + db ----
    const int fb = bx - PW_BLK;
    const int l = fb >> 3, xi = fb & 7;
    const int i = (xi << 4) + lanelo;
    const float* f2o_l = f2o + (size_t)l * 16384;
    const float* dw_l = dw + (size_t)l * 16384;
    short* W12T_l = W12T + (size_t)l * 16384;
    f32x4 c[2] = {{0.f, 0.f, 0.f, 0.f}, {0.f, 0.f, 0.f, 0.f}};
#pragma unroll
    for (int kt = 0; kt < 4; ++kt) {
      const int k0 = kt * 32 + quad * 8;
      const bf16x8 b = pack8(*(const float4*)(f2o_l + (size_t)i * 128 + k0),
                             *(const float4*)(f2o_l + (size_t)i * 128 + k0 + 4));
#pragma unroll
      for (int ct = 0; ct < 2; ++ct) {
        const int j = wbase + ct * 16 + lanelo;
        bf16x8 a;
#pragma unroll
        for (int q = 0; q < 8; ++q) a[q] = f2bf(dw_l[(size_t)(k0 + q) * 128 + j]);
        c[ct] = __builtin_amdgcn_mfma_f32_16x16x32_bf16(a, b, c[ct], 0, 0, 0);
      }
    }
#pragma unroll
    for (int ct = 0; ct < 2; ++ct)
#pragma unroll
      for (int reg = 0; reg < 4; ++reg) {
        const int j = wbase + ct * 16 + quad * 4 + reg;
        W12T_l[(size_t)j * 128 + i] = f2bf(c[ct][reg]);
      }
    if (xi == 0 && t < 128) {
      float acc = db[(size_t)l * 128 + t];
      for (int k = 0; k < 128; ++k)
        acc += f2ob[(size_t)l * 128 + k] * dw_l[(size_t)k * 128 + t];
      b12[(size_t)l * 128 + t] = acc;
    }
    return;
  }
  // ---- embY = emb @ in2f[0] -> bf16 ----
  const int z = ((bx - PW_BLK - PF_BLK) << 4) + lanelo;
  const int zc = (z < 100) ? z : 99;
  f32x4 c[2] = {{0.f, 0.f, 0.f, 0.f}, {0.f, 0.f, 0.f, 0.f}};
#pragma unroll
  for (int kt = 0; kt < 4; ++kt) {
    const int k0 = kt * 32 + quad * 8;
    const bf16x8 b = pack8(*(const float4*)(emb + (size_t)zc * 128 + k0),
                           *(const float4*)(emb + (size_t)zc * 128 + k0 + 4));
#pragma unroll
    for (int ct = 0; ct < 2; ++ct) {
      const bf16x8 a = *(const bf16x8*)(in2fT + (wbase + ct * 16 + lanelo) * 128 + k0);
      c[ct] = __builtin_amdgcn_mfma_f32_16x16x32_bf16(a, b, c[ct], 0, 0, 0);
    }
  }
  if (z < 100) {
#pragma unroll
    for (int ct = 0; ct < 2; ++ct) {
      const int c0 = wbase + ct * 16 + quad * 4;
      uint2 pk; pk.x = pk2bf(c[ct][0], c[ct][1]); pk.y = pk2bf(c[ct][2], c[ct][3]);
      *(uint2*)(embYB + (size_t)z * 128 + c0) = pk;
    }
  }
}

// ================= prep B: vang GEMM + init gather =========================
__global__ __launch_bounds__(256) void k_prepB(
    const float* __restrict__ Gi, const short* __restrict__ awT,
    const int* __restrict__ zn, const float* __restrict__ emb,
    const short* __restrict__ embYB,
    float* __restrict__ vang, float* __restrict__ x, short* __restrict__ yB) {
  const int bx = blockIdx.x;
  const int t = threadIdx.x;
  if (bx < 768) {
    const int lane = t & 63, wave = t >> 6;
    const int lanelo = lane & 15, quad = lane >> 4;
    const int wbase = wave << 5;
    const int l = bx >> 8;
    const int row = ((bx & 255) << 4) + lanelo;
    const short* aw = awT + (size_t)l * 128 * NGA;
    f32x4 c[2] = {{0.f, 0.f, 0.f, 0.f}, {0.f, 0.f, 0.f, 0.f}};
#pragma unroll
    for (int kt = 0; kt < 16; ++kt) {
      const int k0 = kt * 32 + quad * 8;
      const bf16x8 b = pack8(*(const float4*)(Gi + (size_t)row * NGA + k0),
                             *(const float4*)(Gi + (size_t)row * NGA + k0 + 4));
#pragma unroll
      for (int ct = 0; ct < 2; ++ct) {
        const bf16x8 a = *(const bf16x8*)(aw + (size_t)(wbase + ct * 16 + lanelo) * NGA + k0);
        c[ct] = __builtin_amdgcn_mfma_f32_16x16x32_bf16(a, b, c[ct], 0, 0, 0);
      }
    }
    float* vrow = vang + ((size_t)l * NB * NA + row) * 128;
#pragma unroll
    for (int ct = 0; ct < 2; ++ct) {
      float4 o = make_float4(c[ct][0], c[ct][1], c[ct][2], c[ct][3]);
      *(float4*)(vrow + wbase + ct * 16 + quad * 4) = o;
    }
    return;
  }
  const int ga = (bx - 768) * 2 + (t >> 7);
  const int tt = t & 127;
  const int z = zn[ga];
  x[(size_t)ga * 128 + tt] = emb[(size_t)z * 128 + tt];
  yB[(size_t)ga * 128 + tt] = embYB[(size_t)z * 128 + tt];
}

// ================= fused CFConv: 1 atom/block, in-register gaussians =======
// 256 thr = 4 waves. phase1: wave w owns j-tile w (j=w*16+lanelo, all 128 f,
// gauss B-frag built in-register). phase2: wave w owns f-cols [w*32,+32).
#define HPAD 136
__global__ __launch_bounds__(256) void k_cfconv(
    const float* __restrict__ pos, const int* __restrict__ nbr,
    const int* __restrict__ nmask, const short* __restrict__ yB,
    const short* __restrict__ w1T, const float* __restrict__ b1,
    const short* __restrict__ w2T, const float* __restrict__ b2,
    short* __restrict__ aggB) {
  __shared__ alignas(16) short sH[NN * HPAD];   // 17408 B; aliased as sPart at end
  __shared__ float sR[NN];
  __shared__ float sScale[NN];
  __shared__ int sNbr[NN];

  const int t = threadIdx.x;
  const int ga = blockIdx.x;
  const int b0 = ga & ~(NA - 1);
  const int lane = t & 63;
  const int wave = t >> 6;
  const int lanelo = lane & 15;
  const int quad = lane >> 4;
  const int wbase = wave << 5;     // phase-2: 32 f-cols per wave

  // phase-2 weight fragments
  bf16x8 bw2[8];
#pragma unroll
  for (int ct = 0; ct < 2; ++ct) {
    const int n = wbase + ct * 16 + lanelo;
#pragma unroll
    for (int kt = 0; kt < 4; ++kt)
      bw2[ct * 4 + kt] = *(const bf16x8*)(w2T + n * 128 + kt * 32 + quad * 8);
  }
  float b2r[2];
#pragma unroll
  for (int ct = 0; ct < 2; ++ct) b2r[ct] = b2[wbase + ct * 16 + lanelo];

  if (t < NN) {
    const int nj = nbr[(size_t)ga * NN + t];
    sNbr[t] = nj;
    const float px = pos[(size_t)ga * 3];
    const float py = pos[(size_t)ga * 3 + 1];
    const float pz = pos[(size_t)ga * 3 + 2];
    const float* pj = pos + (size_t)(b0 + nj) * 3;
    const float dx = pj[0] - px, dy = pj[1] - py, dz = pj[2] - pz;
    const float r = sqrtf(dx * dx + dy * dy + dz * dz + 1e-12f);
    sR[t] = r;
    sScale[t] = (r <= 5.0f && nmask[(size_t)ga * NN + t] != 0) ? 1.0f : 0.0f;
  }
  __syncthreads();

  // ---- phase 1: wave w handles j = w*16+lanelo over all 128 f ----
  {
    const float step = 3.8f / 24.0f;
    const float coef = -0.5f / (step * step);
    const int j = wave * 16 + lanelo;
    const float r = sR[j];
    bf16x8 gb;
#pragma unroll
    for (int i = 0; i < 8; ++i) {
      const int g = quad * 8 + i;
      const float d = r - (1.2f + step * (float)g);
      gb[i] = (g < NG) ? f2bf(__expf(coef * d * d)) : (short)0;
    }
#pragma unroll
    for (int ct = 0; ct < 8; ++ct) {
      const bf16x8 aw1 = *(const bf16x8*)(w1T + (ct * 16 + lanelo) * 32 + quad * 8);
      f32x4 c = {0.f, 0.f, 0.f, 0.f};
      c = __builtin_amdgcn_mfma_f32_16x16x32_bf16(aw1, gb, c, 0, 0, 0);
      // C: col(lanelo)=j-local, row(quad*4+reg)=f-local -> f = ct*16+quad*4+reg
      const int f0 = ct * 16 + quad * 4;
      const float4 bv = *(const float4*)(b1 + f0);
      uint2 pk;
      pk.x = pk2bf(sspf(c[0] + bv.x), sspf(c[1] + bv.y));
      pk.y = pk2bf(sspf(c[2] + bv.z), sspf(c[3] + bv.w));
      *(uint2*)(sH + j * HPAD + f0) = pk;
    }
  }
  __syncthreads();

  // ---- phase 2: W = h @ w2 (+b2 via C-init); consume against global bf16 y ----
  float pagg[2] = {0.f, 0.f};
#pragma unroll
  for (int rt = 0; rt < 4; ++rt) {
    f32x4 acc[2];
    acc[0] = (f32x4){b2r[0], b2r[0], b2r[0], b2r[0]};
    acc[1] = (f32x4){b2r[1], b2r[1], b2r[1], b2r[1]};
#pragma unroll
    for (int kt = 0; kt < 4; ++kt) {
      const bf16x8 ah = *(const bf16x8*)(sH + (rt * 16 + lanelo) * HPAD + kt * 32 + quad * 8);
#pragma unroll
      for (int ct = 0; ct < 2; ++ct)
        acc[ct] = __builtin_amdgcn_mfma_f32_16x16x32_bf16(ah, bw2[ct * 4 + kt], acc[ct], 0, 0, 0);
    }
#pragma unroll
    for (int reg = 0; reg < 4; ++reg) {
      const int j = rt * 16 + quad * 4 + reg;
      const float sc = sScale[j];
      const unsigned short* yr =
          (const unsigned short*)(yB + (size_t)(b0 + sNbr[j]) * NF) + wbase + lanelo;
#pragma unroll
      for (int ct = 0; ct < 2; ++ct)
        pagg[ct] = fmaf(sc * acc[ct][reg], bf2f(yr[ct * 16]), pagg[ct]);
    }
  }

  __syncthreads();                 // sH reads done -> alias as sPart [4][128] fp32
  float* sPart = (float*)sH;
#pragma unroll
  for (int ct = 0; ct < 2; ++ct)
    sPart[quad * NF + wbase + ct * 16 + lanelo] = pagg[ct];
  __syncthreads();
  if (t < NF)
    aggB[(size_t)ga * NF + t] =
        f2bf(sPart[t] + sPart[NF + t] + sPart[2 * NF + t] + sPart[3 * NF + t]);
}

// ================= per-layer update (fused W12, 2 GEMMs) ===================
#define TPAD 136
__global__ __launch_bounds__(256) void k_upd(
    float* __restrict__ x, const short* __restrict__ aggB,
    const float* __restrict__ vang,
    const short* __restrict__ W12Tl, const float* __restrict__ b12l,
    const short* __restrict__ in2fT, short* __restrict__ yB) {
  __shared__ alignas(16) short sT[16 * TPAD];
  const int t = threadIdx.x;
  const int lane = t & 63, wave = t >> 6;
  const int lanelo = lane & 15, quad = lane >> 4;
  const int wbase = wave << 5;               // 4 waves x 32 cols
  const int row = (blockIdx.x << 4) + lanelo;

  // GEMM_A: v = aggB @ W12T
  f32x4 c2[2] = {{0.f, 0.f, 0.f, 0.f}, {0.f, 0.f, 0.f, 0.f}};
#pragma unroll
  for (int kt = 0; kt < 4; ++kt) {
    const bf16x8 b = *(const bf16x8*)(aggB + (size_t)row * 128 + kt * 32 + quad * 8);
#pragma unroll
    for (int ct = 0; ct < 2; ++ct) {
      const bf16x8 a = *(const bf16x8*)(W12Tl + (wbase + ct * 16 + lanelo) * 128 + kt * 32 + quad * 8);
      c2[ct] = __builtin_amdgcn_mfma_f32_16x16x32_bf16(a, b, c2[ct], 0, 0, 0);
    }
  }

  // epilogue: x += ssp(v + b12 + vang); stage x_new bf16
#pragma unroll
  for (int ct = 0; ct < 2; ++ct) {
    const int c0 = wbase + ct * 16 + quad * 4;
    const float4 dv = *(const float4*)(b12l + c0);
    const float4 vv = *(const float4*)(vang + (size_t)row * 128 + c0);
    float* xp = x + (size_t)row * 128 + c0;
    const float4 xv = *(const float4*)xp;
    float4 xo;
    xo.x = xv.x + sspf(c2[ct][0] + vv.x + dv.x);
    xo.y = xv.y + sspf(c2[ct][1] + vv.y + dv.y);
    xo.z = xv.z + sspf(c2[ct][2] + vv.z + dv.z);
    xo.w = xv.w + sspf(c2[ct][3] + vv.w + dv.w);
    *(float4*)xp = xo;
    if (in2fT != nullptr) {
      uint2 pk; pk.x = pk2bf(xo.x, xo.y); pk.y = pk2bf(xo.z, xo.w);
      *(uint2*)(sT + lanelo * TPAD + c0) = pk;
    }
  }
  if (in2fT == nullptr) return;
  __syncthreads();

  // GEMM_B: yB = x_new @ in2fT (bf16 out)
  f32x4 c3[2] = {{0.f, 0.f, 0.f, 0.f}, {0.f, 0.f, 0.f, 0.f}};
#pragma unroll
  for (int kt = 0; kt < 4; ++kt) {
    const bf16x8 b = *(const bf16x8*)(sT + lanelo * TPAD + kt * 32 + quad * 8);
#pragma unroll
    for (int ct = 0; ct < 2; ++ct) {
      const bf16x8 a = *(const bf16x8*)(in2fT + (wbase + ct * 16 + lanelo) * 128 + kt * 32 + quad * 8);
      c3[ct] = __builtin_amdgcn_mfma_f32_16x16x32_bf16(a, b, c3[ct], 0, 0, 0);
    }
  }
#pragma unroll
  for (int ct = 0; ct < 2; ++ct) {
    const int c0 = wbase + ct * 16 + quad * 4;
    uint2 pk; pk.x = pk2bf(c3[ct][0], c3[ct][1]); pk.y = pk2bf(c3[ct][2], c3[ct][3]);
    *(uint2*)(yB + (size_t)row * 128 + c0) = pk;
  }
}

extern "C" void kernel_launch(void* const* d_in, const int* in_sizes, int n_in,
                              void* d_out, int out_size, void* d_ws, size_t ws_size,
                              hipStream_t stream) {
  (void)in_sizes; (void)n_in; (void)out_size; (void)ws_size;
  const int* zn = (const int*)d_in[0];
  const float* pos = (const float*)d_in[1];
  const int* nbr = (const int*)d_in[2];
  const int* nmask = (const int*)d_in[3];
  const float* Gi = (const float*)d_in[4];
  const float* emb = (const float*)d_in[5];
  const float* fw1 = (const float*)d_in[6];
  const float* fb1 = (const float*)d_in[7];
  const float* fw2 = (const float*)d_in[8];
  const float* fb2 = (const float*)d_in[9];
  const float* in2f = (const float*)d_in[10];
  const float* f2o = (const float*)d_in[11];
  const float* f2ob = (const float*)d_in[12];
  const float* dwp = (const float*)d_in[13];
  const float* dbp = (const float*)d_in[14];
  const float* awp = (const float*)d_in[15];

  float* x = (float*)d_out;                            // [B,A,D] fp32
  float* vang = (float*)d_ws;                          // [3][B*A][128] fp32
  float* b12 = vang + (size_t)3 * NB * NA * ND;        // [3][128] fp32
  short* yB = (short*)(b12 + 3 * 128);                 // [B,A,F] bf16
  short* aggB = yB + (size_t)NB * NA * NF;             // [B,A,F] bf16
  short* w1T = aggB + (size_t)NB * NA * NF;            // [3][128][32]
  short* w2T = w1T + NW1;                              // [3][128][128]
  short* in2fT = w2T + NSQ;                            // [3][128][128]
  short* awT = in2fT + NSQ;                            // [3][128][512]
  short* W12T = awT + NAW;                             // [3][128][128]
  short* embYB = W12T + NSQ;                           // [112][128]

  k_prepA<<<PW_BLK + PF_BLK + PE_BLK, 256, 0, stream>>>(
      fw1, fw2, in2f, awp, f2o, f2ob, dwp, dbp, emb,
      w1T, w2T, in2fT, awT, W12T, b12, embYB);
  k_prepB<<<768 + NB * NA / 2, 256, 0, stream>>>(
      Gi, awT, zn, emb, embYB, vang, x, yB);
  for (int l = 0; l < 3; ++l) {
    k_cfconv<<<NB * NA, 256, 0, stream>>>(pos, nbr, nmask, yB,
        w1T + (size_t)l * 128 * 32, fb1 + (size_t)l * NF,
        w2T + (size_t)l * 128 * 128, fb2 + (size_t)l * NF, aggB);
    k_upd<<<NB * NA / 16, 256, 0, stream>>>(x, aggB,
        vang + (size_t)l * NB * NA * ND,
        W12T + (size_t)l * 16384, b12 + (size_t)l * 128,
        (l < 2) ? (in2fT + (size_t)(l + 1) * 16384) : nullptr, yB);
  }
}

// Round 11
// 223.487 us; speedup vs baseline: 1.3560x; 1.1818x over previous
//
#include <hip/hip_runtime.h>
#include <math.h>

#define NB 8
#define NA 512
#define NN 64
#define ND 128
#define NF 128
#define NG 25
#define NGA 512

typedef __attribute__((ext_vector_type(8))) short bf16x8;
typedef __attribute__((ext_vector_type(4))) float f32x4;

__device__ __forceinline__ float sspf(float v) {
  return fmaxf(v, 0.0f) + __logf(1.0f + __expf(-fabsf(v))) - 0.6931471805599453f;
}

__device__ __forceinline__ short f2bf(float x) {
  union { float f; unsigned u; } v; v.f = x;
  unsigned r = v.u + 0x7fffu + ((v.u >> 16) & 1u);   // RNE
  return (short)(r >> 16);
}

#if defined(__has_builtin)
#if __has_builtin(__builtin_amdgcn_cvt_pk_bf16_f32)
#define HAS_PKBF 1
#endif
#endif

__device__ __forceinline__ unsigned pk2bf(float a, float b) {
#ifdef HAS_PKBF
  typedef __attribute__((ext_vector_type(2))) __bf16 v2bf;
  union { v2bf v; unsigned u; } c;
  c.v = __builtin_amdgcn_cvt_pk_bf16_f32(a, b);
  return c.u;
#else
  union { float f; unsigned u; } x, y; x.f = a; y.f = b;
  const unsigned ra = (x.u + 0x7fffu + ((x.u >> 16) & 1u)) >> 16;
  const unsigned rb = (y.u + 0x7fffu + ((y.u >> 16) & 1u)) & 0xffff0000u;
  return ra | rb;
#endif
}

__device__ __forceinline__ float bf2f(unsigned short us) {
  union { unsigned u; float f; } v; v.u = ((unsigned)us) << 16; return v.f;
}

__device__ __forceinline__ bf16x8 pack8(float4 a, float4 b) {
  bf16x8 r;
  unsigned* p = (unsigned*)&r;
  p[0] = pk2bf(a.x, a.y); p[1] = pk2bf(a.z, a.w);
  p[2] = pk2bf(b.x, b.y); p[3] = pk2bf(b.z, b.w);
  return r;
}

#define NW1 (3 * 128 * 32)      // 12288
#define NSQ (3 * 128 * 128)     // 49152
#define NAW (3 * 128 * 512)     // 196608
#define PW_BLK ((NW1 + 2 * NSQ + NAW) / 256)   // 1200
#define PF_BLK 24
#define PE_BLK 7

// ================= prep A: weights bf16-T, W12 fuse, embY ==================
__global__ __launch_bounds__(256) void k_prepA(
    const float* __restrict__ fw1, const float* __restrict__ fw2,
    const float* __restrict__ in2f, const float* __restrict__ aw,
    const float* __restrict__ f2o, const float* __restrict__ f2ob,
    const float* __restrict__ dw, const float* __restrict__ db,
    const float* __restrict__ emb,
    short* __restrict__ w1T, short* __restrict__ w2T,
    short* __restrict__ in2fT, short* __restrict__ awT,
    short* __restrict__ W12T, float* __restrict__ b12,
    short* __restrict__ embYB) {
  const int bx = blockIdx.x;
  const int t = threadIdx.x;
  if (bx < PW_BLK) {
    int idx = bx * 256 + t;
    if (idx < NW1) {
      const int l = idx >> 12, r = idx & 4095, n = r >> 5, k = r & 31;
      w1T[idx] = (k < NG) ? f2bf(fw1[(size_t)l * NG * NF + k * NF + n]) : (short)0;
      return;
    }
    idx -= NW1;
    if (idx < 2 * NSQ) {
      const int which = idx / NSQ, q = idx % NSQ;
      const int l = q >> 14, r = q & 16383, n = r >> 7, k = r & 127;
      const float* src = (which == 0) ? fw2 : in2f;
      short* dst = (which == 0) ? w2T : in2fT;
      dst[q] = f2bf(src[(size_t)l * 16384 + k * 128 + n]);
      return;
    }
    idx -= 2 * NSQ;
    if (idx < NAW) {
      const int l = idx >> 16, r = idx & 65535, n = r >> 9, k = r & 511;
      awT[idx] = f2bf(aw[(size_t)l * 65536 + k * 128 + n]);
    }
    return;
  }
  const int lane = t & 63, wave = t >> 6;
  const int lanelo = lane & 15, quad = lane >> 4;
  const int wbase = wave << 5;
  if (bx < PW_BLK + PF_BLK) {
    // ---- W12 = f2o@dw (bf16), b12 = f2ob@dw + db ----
    const int fb = bx - PW_BLK;
    const int l = fb >> 3, xi = fb & 7;
    const int i = (xi << 4) + lanelo;
    const float* f2o_l = f2o + (size_t)l * 16384;
    const float* dw_l = dw + (size_t)l * 16384;
    short* W12T_l = W12T + (size_t)l * 16384;
    f32x4 c[2] = {{0.f, 0.f, 0.f, 0.f}, {0.f, 0.f, 0.f, 0.f}};
#pragma unroll
    for (int kt = 0; kt < 4; ++kt) {
      const int k0 = kt * 32 + quad * 8;
      const bf16x8 b = pack8(*(const float4*)(f2o_l + (size_t)i * 128 + k0),
                             *(const float4*)(f2o_l + (size_t)i * 128 + k0 + 4));
#pragma unroll
      for (int ct = 0; ct < 2; ++ct) {
        const int j = wbase + ct * 16 + lanelo;
        bf16x8 a;
#pragma unroll
        for (int q = 0; q < 8; ++q) a[q] = f2bf(dw_l[(size_t)(k0 + q) * 128 + j]);
        c[ct] = __builtin_amdgcn_mfma_f32_16x16x32_bf16(a, b, c[ct], 0, 0, 0);
      }
    }
#pragma unroll
    for (int ct = 0; ct < 2; ++ct)
#pragma unroll
      for (int reg = 0; reg < 4; ++reg) {
        const int j = wbase + ct * 16 + quad * 4 + reg;
        W12T_l[(size_t)j * 128 + i] = f2bf(c[ct][reg]);
      }
    if (xi == 0 && t < 128) {
      float acc = db[(size_t)l * 128 + t];
      for (int k = 0; k < 128; ++k)
        acc += f2ob[(size_t)l * 128 + k] * dw_l[(size_t)k * 128 + t];
      b12[(size_t)l * 128 + t] = acc;
    }
    return;
  }
  // ---- embY = emb @ in2f[0] -> bf16 ----
  const int z = ((bx - PW_BLK - PF_BLK) << 4) + lanelo;
  const int zc = (z < 100) ? z : 99;
  f32x4 c[2] = {{0.f, 0.f, 0.f, 0.f}, {0.f, 0.f, 0.f, 0.f}};
#pragma unroll
  for (int kt = 0; kt < 4; ++kt) {
    const int k0 = kt * 32 + quad * 8;
    const bf16x8 b = pack8(*(const float4*)(emb + (size_t)zc * 128 + k0),
                           *(const float4*)(emb + (size_t)zc * 128 + k0 + 4));
#pragma unroll
    for (int ct = 0; ct < 2; ++ct) {
      const bf16x8 a = *(const bf16x8*)(in2fT + (wbase + ct * 16 + lanelo) * 128 + k0);
      c[ct] = __builtin_amdgcn_mfma_f32_16x16x32_bf16(a, b, c[ct], 0, 0, 0);
    }
  }
  if (z < 100) {
#pragma unroll
    for (int ct = 0; ct < 2; ++ct) {
      const int c0 = wbase + ct * 16 + quad * 4;
      uint2 pk; pk.x = pk2bf(c[ct][0], c[ct][1]); pk.y = pk2bf(c[ct][2], c[ct][3]);
      *(uint2*)(embYB + (size_t)z * 128 + c0) = pk;
    }
  }
}

// ================= prep B: vang GEMM + init gather =========================
__global__ __launch_bounds__(256) void k_prepB(
    const float* __restrict__ Gi, const short* __restrict__ awT,
    const int* __restrict__ zn, const float* __restrict__ emb,
    const short* __restrict__ embYB,
    float* __restrict__ vang, float* __restrict__ x, short* __restrict__ yB) {
  const int bx = blockIdx.x;
  const int t = threadIdx.x;
  if (bx < 768) {
    const int lane = t & 63, wave = t >> 6;
    const int lanelo = lane & 15, quad = lane >> 4;
    const int wbase = wave << 5;
    const int l = bx >> 8;
    const int row = ((bx & 255) << 4) + lanelo;
    const short* aw = awT + (size_t)l * 128 * NGA;
    f32x4 c[2] = {{0.f, 0.f, 0.f, 0.f}, {0.f, 0.f, 0.f, 0.f}};
#pragma unroll
    for (int kt = 0; kt < 16; ++kt) {
      const int k0 = kt * 32 + quad * 8;
      const bf16x8 b = pack8(*(const float4*)(Gi + (size_t)row * NGA + k0),
                             *(const float4*)(Gi + (size_t)row * NGA + k0 + 4));
#pragma unroll
      for (int ct = 0; ct < 2; ++ct) {
        const bf16x8 a = *(const bf16x8*)(aw + (size_t)(wbase + ct * 16 + lanelo) * NGA + k0);
        c[ct] = __builtin_amdgcn_mfma_f32_16x16x32_bf16(a, b, c[ct], 0, 0, 0);
      }
    }
    float* vrow = vang + ((size_t)l * NB * NA + row) * 128;
#pragma unroll
    for (int ct = 0; ct < 2; ++ct) {
      float4 o = make_float4(c[ct][0], c[ct][1], c[ct][2], c[ct][3]);
      *(float4*)(vrow + wbase + ct * 16 + quad * 4) = o;
    }
    return;
  }
  const int ga = (bx - 768) * 2 + (t >> 7);
  const int tt = t & 127;
  const int z = zn[ga];
  x[(size_t)ga * 128 + tt] = emb[(size_t)z * 128 + tt];
  yB[(size_t)ga * 128 + tt] = embYB[(size_t)z * 128 + tt];
}

// ================= fused CFConv with neighbor compaction ===================
// Valid neighbors (mask && r<=cutoff) are compacted to the front (avg ~10/64),
// tiles of 16 rows; typically ntiles==1 -> ~4x less activation+epilogue work.
// phase1: wave w owns f-cols [w*32,+32), loops j-tiles; gauss frag in-register.
// phase2: wave w owns same f-cols; reduction over quads via LDS.
#define HPAD 136
__global__ __launch_bounds__(256) void k_cfconv(
    const float* __restrict__ pos, const int* __restrict__ nbr,
    const int* __restrict__ nmask, const short* __restrict__ yB,
    const short* __restrict__ w1T, const float* __restrict__ b1,
    const short* __restrict__ w2T, const float* __restrict__ b2,
    short* __restrict__ aggB) {
  __shared__ alignas(16) short sH[NN * HPAD];   // aliased as sPart at end
  __shared__ float sR[NN];
  __shared__ float sScale[NN];
  __shared__ int sNbr[NN];
  __shared__ int sNv;

  const int t = threadIdx.x;
  const int ga = blockIdx.x;
  const int b0 = ga & ~(NA - 1);
  const int lane = t & 63;
  const int wave = t >> 6;
  const int lanelo = lane & 15;
  const int quad = lane >> 4;
  const int wbase = wave << 5;     // this wave's 32 f-cols

  // weight fragments for this wave's f-cols
  bf16x8 bw1[2];
  bf16x8 bw2[8];
#pragma unroll
  for (int ct = 0; ct < 2; ++ct) {
    const int n = wbase + ct * 16 + lanelo;
    bw1[ct] = *(const bf16x8*)(w1T + n * 32 + quad * 8);
#pragma unroll
    for (int kt = 0; kt < 4; ++kt)
      bw2[ct * 4 + kt] = *(const bf16x8*)(w2T + n * 128 + kt * 32 + quad * 8);
  }
  float b2r[2];
#pragma unroll
  for (int ct = 0; ct < 2; ++ct) b2r[ct] = b2[wbase + ct * 16 + lanelo];
  float4 b1v[2];
#pragma unroll
  for (int ct = 0; ct < 2; ++ct)
    b1v[ct] = *(const float4*)(b1 + wbase + ct * 16 + quad * 4);

  // ---- wave 0: distances + ballot compaction ----
  if (t < NN) {
    const int nj = nbr[(size_t)ga * NN + t];
    const float px = pos[(size_t)ga * 3];
    const float py = pos[(size_t)ga * 3 + 1];
    const float pz = pos[(size_t)ga * 3 + 2];
    const float* pj = pos + (size_t)(b0 + nj) * 3;
    const float dx = pj[0] - px, dy = pj[1] - py, dz = pj[2] - pz;
    const float r = sqrtf(dx * dx + dy * dy + dz * dz + 1e-12f);
    const bool valid = (r <= 5.0f) && (nmask[(size_t)ga * NN + t] != 0);
    // defaults (pad rows): written first, then compacted entries overwrite
    sR[t] = 1.0f; sScale[t] = 0.0f; sNbr[t] = 0;
    const unsigned long long m = __ballot(valid);
    const int pos_c = __popcll(m & ((1ull << lane) - 1ull));
    if (valid) { sNbr[pos_c] = nj; sR[pos_c] = r; sScale[pos_c] = 1.0f; }
    if (lane == 0) sNv = (int)__popcll(m);
  }
  __syncthreads();

  const int ntiles = (sNv + 15) >> 4;   // uniform across block

  const float step = 3.8f / 24.0f;
  const float coef = -0.5f / (step * step);

  // ---- phase 1: h = ssp(f @ w1 + b1) for compacted tiles ----
  for (int jt = 0; jt < ntiles; ++jt) {
    const int j = jt * 16 + lanelo;
    const float r = sR[j];
    bf16x8 gb;
    {
      float e[8];
#pragma unroll
      for (int i = 0; i < 8; ++i) {
        const int g = quad * 8 + i;
        const float d = r - (1.2f + step * (float)g);
        e[i] = (g < NG) ? __expf(coef * d * d) : 0.0f;
      }
      unsigned* gp = (unsigned*)&gb;
      gp[0] = pk2bf(e[0], e[1]); gp[1] = pk2bf(e[2], e[3]);
      gp[2] = pk2bf(e[4], e[5]); gp[3] = pk2bf(e[6], e[7]);
    }
#pragma unroll
    for (int ct = 0; ct < 2; ++ct) {
      f32x4 c = {0.f, 0.f, 0.f, 0.f};
      c = __builtin_amdgcn_mfma_f32_16x16x32_bf16(bw1[ct], gb, c, 0, 0, 0);
      // C: col(lanelo)=j-local, row(quad*4+reg)=f-local
      const int f0 = wbase + ct * 16 + quad * 4;
      uint2 pk;
      pk.x = pk2bf(sspf(c[0] + b1v[ct].x), sspf(c[1] + b1v[ct].y));
      pk.y = pk2bf(sspf(c[2] + b1v[ct].z), sspf(c[3] + b1v[ct].w));
      *(uint2*)(sH + j * HPAD + f0) = pk;
    }
  }
  __syncthreads();

  // ---- phase 2: W = h @ w2 (+b2 via C-init); consume against global bf16 y ----
  float pagg[2] = {0.f, 0.f};
  for (int rt = 0; rt < ntiles; ++rt) {
    f32x4 acc[2];
    acc[0] = (f32x4){b2r[0], b2r[0], b2r[0], b2r[0]};
    acc[1] = (f32x4){b2r[1], b2r[1], b2r[1], b2r[1]};
#pragma unroll
    for (int kt = 0; kt < 4; ++kt) {
      const bf16x8 ah = *(const bf16x8*)(sH + (rt * 16 + lanelo) * HPAD + kt * 32 + quad * 8);
#pragma unroll
      for (int ct = 0; ct < 2; ++ct)
        acc[ct] = __builtin_amdgcn_mfma_f32_16x16x32_bf16(ah, bw2[ct * 4 + kt], acc[ct], 0, 0, 0);
    }
#pragma unroll
    for (int reg = 0; reg < 4; ++reg) {
      const int j = rt * 16 + quad * 4 + reg;
      const float sc = sScale[j];
      const unsigned short* yr =
          (const unsigned short*)(yB + (size_t)(b0 + sNbr[j]) * NF) + wbase + lanelo;
#pragma unroll
      for (int ct = 0; ct < 2; ++ct)
        pagg[ct] = fmaf(sc * acc[ct][reg], bf2f(yr[ct * 16]), pagg[ct]);
    }
  }

  __syncthreads();                 // sH reads done -> alias as sPart [4][128] fp32
  float* sPart = (float*)sH;
#pragma unroll
  for (int ct = 0; ct < 2; ++ct)
    sPart[quad * NF + wbase + ct * 16 + lanelo] = pagg[ct];
  __syncthreads();
  if (t < NF)
    aggB[(size_t)ga * NF + t] =
        f2bf(sPart[t] + sPart[NF + t] + sPart[2 * NF + t] + sPart[3 * NF + t]);
}

// ================= per-layer update (fused W12, 2 GEMMs) ===================
#define TPAD 136
__global__ __launch_bounds__(256) void k_upd(
    float* __restrict__ x, const short* __restrict__ aggB,
    const float* __restrict__ vang,
    const short* __restrict__ W12Tl, const float* __restrict__ b12l,
    const short* __restrict__ in2fT, short* __restrict__ yB) {
  __shared__ alignas(16) short sT[16 * TPAD];
  const int t = threadIdx.x;
  const int lane = t & 63, wave = t >> 6;
  const int lanelo = lane & 15, quad = lane >> 4;
  const int wbase = wave << 5;               // 4 waves x 32 cols
  const int row = (blockIdx.x << 4) + lanelo;

  // GEMM_A: v = aggB @ W12T
  f32x4 c2[2] = {{0.f, 0.f, 0.f, 0.f}, {0.f, 0.f, 0.f, 0.f}};
#pragma unroll
  for (int kt = 0; kt < 4; ++kt) {
    const bf16x8 b = *(const bf16x8*)(aggB + (size_t)row * 128 + kt * 32 + quad * 8);
#pragma unroll
    for (int ct = 0; ct < 2; ++ct) {
      const bf16x8 a = *(const bf16x8*)(W12Tl + (wbase + ct * 16 + lanelo) * 128 + kt * 32 + quad * 8);
      c2[ct] = __builtin_amdgcn_mfma_f32_16x16x32_bf16(a, b, c2[ct], 0, 0, 0);
    }
  }

  // epilogue: x += ssp(v + b12 + vang); stage x_new bf16
#pragma unroll
  for (int ct = 0; ct < 2; ++ct) {
    const int c0 = wbase + ct * 16 + quad * 4;
    const float4 dv = *(const float4*)(b12l + c0);
    const float4 vv = *(const float4*)(vang + (size_t)row * 128 + c0);
    float* xp = x + (size_t)row * 128 + c0;
    const float4 xv = *(const float4*)xp;
    float4 xo;
    xo.x = xv.x + sspf(c2[ct][0] + vv.x + dv.x);
    xo.y = xv.y + sspf(c2[ct][1] + vv.y + dv.y);
    xo.z = xv.z + sspf(c2[ct][2] + vv.z + dv.z);
    xo.w = xv.w + sspf(c2[ct][3] + vv.w + dv.w);
    *(float4*)xp = xo;
    if (in2fT != nullptr) {
      uint2 pk; pk.x = pk2bf(xo.x, xo.y); pk.y = pk2bf(xo.z, xo.w);
      *(uint2*)(sT + lanelo * TPAD + c0) = pk;
    }
  }
  if (in2fT == nullptr) return;
  __syncthreads();

  // GEMM_B: yB = x_new @ in2fT (bf16 out)
  f32x4 c3[2] = {{0.f, 0.f, 0.f, 0.f}, {0.f, 0.f, 0.f, 0.f}};
#pragma unroll
  for (int kt = 0; kt < 4; ++kt) {
    const bf16x8 b = *(const bf16x8*)(sT + lanelo * TPAD + kt * 32 + quad * 8);
#pragma unroll
    for (int ct = 0; ct < 2; ++ct) {
      const bf16x8 a = *(const bf16x8*)(in2fT + (wbase + ct * 16 + lanelo) * 128 + kt * 32 + quad * 8);
      c3[ct] = __builtin_amdgcn_mfma_f32_16x16x32_bf16(a, b, c3[ct], 0, 0, 0);
    }
  }
#pragma unroll
  for (int ct = 0; ct < 2; ++ct) {
    const int c0 = wbase + ct * 16 + quad * 4;
    uint2 pk; pk.x = pk2bf(c3[ct][0], c3[ct][1]); pk.y = pk2bf(c3[ct][2], c3[ct][3]);
    *(uint2*)(yB + (size_t)row * 128 + c0) = pk;
  }
}

extern "C" void kernel_launch(void* const* d_in, const int* in_sizes, int n_in,
                              void* d_out, int out_size, void* d_ws, size_t ws_size,
                              hipStream_t stream) {
  (void)in_sizes; (void)n_in; (void)out_size; (void)ws_size;
  const int* zn = (const int*)d_in[0];
  const float* pos = (const float*)d_in[1];
  const int* nbr = (const int*)d_in[2];
  const int* nmask = (const int*)d_in[3];
  const float* Gi = (const float*)d_in[4];
  const float* emb = (const float*)d_in[5];
  const float* fw1 = (const float*)d_in[6];
  const float* fb1 = (const float*)d_in[7];
  const float* fw2 = (const float*)d_in[8];
  const float* fb2 = (const float*)d_in[9];
  const float* in2f = (const float*)d_in[10];
  const float* f2o = (const float*)d_in[11];
  const float* f2ob = (const float*)d_in[12];
  const float* dwp = (const float*)d_in[13];
  const float* dbp = (const float*)d_in[14];
  const float* awp = (const float*)d_in[15];

  float* x = (float*)d_out;                            // [B,A,D] fp32
  float* vang = (float*)d_ws;                          // [3][B*A][128] fp32
  float* b12 = vang + (size_t)3 * NB * NA * ND;        // [3][128] fp32
  short* yB = (short*)(b12 + 3 * 128);                 // [B,A,F] bf16
  short* aggB = yB + (size_t)NB * NA * NF;             // [B,A,F] bf16
  short* w1T = aggB + (size_t)NB * NA * NF;            // [3][128][32]
  short* w2T = w1T + NW1;                              // [3][128][128]
  short* in2fT = w2T + NSQ;                            // [3][128][128]
  short* awT = in2fT + NSQ;                            // [3][128][512]
  short* W12T = awT + NAW;                             // [3][128][128]
  short* embYB = W12T + NSQ;                           // [112][128]

  k_prepA<<<PW_BLK + PF_BLK + PE_BLK, 256, 0, stream>>>(
      fw1, fw2, in2f, awp, f2o, f2ob, dwp, dbp, emb,
      w1T, w2T, in2fT, awT, W12T, b12, embYB);
  k_prepB<<<768 + NB * NA / 2, 256, 0, stream>>>(
      Gi, awT, zn, emb, embYB, vang, x, yB);
  for (int l = 0; l < 3; ++l) {
    k_cfconv<<<NB * NA, 256, 0, stream>>>(pos, nbr, nmask, yB,
        w1T + (size_t)l * 128 * 32, fb1 + (size_t)l * NF,
        w2T + (size_t)l * 128 * 128, fb2 + (size_t)l * NF, aggB);
    k_upd<<<NB * NA / 16, 256, 0, stream>>>(x, aggB,
        vang + (size_t)l * NB * NA * ND,
        W12T + (size_t)l * 16384, b12 + (size_t)l * 128,
        (l < 2) ? (in2fT + (size_t)(l + 1) * 16384) : nullptr, yB);
  }
}

// Round 12
// 213.266 us; speedup vs baseline: 1.4210x; 1.0479x over previous
//
#include <hip/hip_runtime.h>
#include <math.h>

#define NB 8
#define NA 512
#define NN 64
#define ND 128
#define NF 128
#define NG 25
#define NGA 512

typedef __attribute__((ext_vector_type(8))) short bf16x8;
typedef __attribute__((ext_vector_type(4))) float f32x4;

__device__ __forceinline__ float sspf(float v) {
  return fmaxf(v, 0.0f) + __logf(1.0f + __expf(-fabsf(v))) - 0.6931471805599453f;
}

__device__ __forceinline__ short f2bf(float x) {
  union { float f; unsigned u; } v; v.f = x;
  unsigned r = v.u + 0x7fffu + ((v.u >> 16) & 1u);   // RNE
  return (short)(r >> 16);
}

#if defined(__has_builtin)
#if __has_builtin(__builtin_amdgcn_cvt_pk_bf16_f32)
#define HAS_PKBF 1
#endif
#endif

__device__ __forceinline__ unsigned pk2bf(float a, float b) {
#ifdef HAS_PKBF
  typedef __attribute__((ext_vector_type(2))) __bf16 v2bf;
  union { v2bf v; unsigned u; } c;
  c.v = __builtin_amdgcn_cvt_pk_bf16_f32(a, b);
  return c.u;
#else
  union { float f; unsigned u; } x, y; x.f = a; y.f = b;
  const unsigned ra = (x.u + 0x7fffu + ((x.u >> 16) & 1u)) >> 16;
  const unsigned rb = (y.u + 0x7fffu + ((y.u >> 16) & 1u)) & 0xffff0000u;
  return ra | rb;
#endif
}

__device__ __forceinline__ float bf2f(unsigned short us) {
  union { unsigned u; float f; } v; v.u = ((unsigned)us) << 16; return v.f;
}

__device__ __forceinline__ bf16x8 pack8(float4 a, float4 b) {
  bf16x8 r;
  unsigned* p = (unsigned*)&r;
  p[0] = pk2bf(a.x, a.y); p[1] = pk2bf(a.z, a.w);
  p[2] = pk2bf(b.x, b.y); p[3] = pk2bf(b.z, b.w);
  return r;
}

// W^T-style fragment built from row-major M[k][n]: elem i = bf16(M[k0q+i][n])
__device__ __forceinline__ bf16x8 fragT(const float* __restrict__ M, int ldn,
                                        int n, int k0q) {
  float e[8];
#pragma unroll
  for (int i = 0; i < 8; ++i) e[i] = M[(size_t)(k0q + i) * ldn + n];
  bf16x8 r; unsigned* p = (unsigned*)&r;
  p[0] = pk2bf(e[0], e[1]); p[1] = pk2bf(e[2], e[3]);
  p[2] = pk2bf(e[4], e[5]); p[3] = pk2bf(e[6], e[7]);
  return r;
}

#define NW1 (3 * 128 * 32)      // 12288
#define NSQ (3 * 128 * 128)     // 49152
// k_prep grid layout (all blocks independent):
#define TT_BLK 96               // 6 square mats x 16 (32x32) tiles
#define W1_BLK 48               // w1T scalar transpose
#define PF_BLK 24               // W12 fuse
#define VA_BLK 768              // vang direct
#define Y0_BLK 256              // y0 + x init
#define B_W1 (TT_BLK)
#define B_PF (B_W1 + W1_BLK)
#define B_VA (B_PF + PF_BLK)
#define B_Y0 (B_VA + VA_BLK)
#define PREP_BLK (B_Y0 + Y0_BLK)   // 1192

// ================= single prep kernel: no inter-block dependencies =========
__global__ __launch_bounds__(256) void k_prep(
    const float* __restrict__ fw1, const float* __restrict__ fw2,
    const float* __restrict__ in2f, const float* __restrict__ aw,
    const float* __restrict__ f2o, const float* __restrict__ f2ob,
    const float* __restrict__ dw, const float* __restrict__ db,
    const float* __restrict__ emb, const float* __restrict__ Gi,
    const int* __restrict__ zn,
    short* __restrict__ w1T, short* __restrict__ w2T,
    short* __restrict__ in2fT, short* __restrict__ W12T,
    float* __restrict__ b12, float* __restrict__ vang,
    float* __restrict__ x, short* __restrict__ yB) {
  __shared__ short sTile[32][33];
  const int bx = blockIdx.x;
  const int t = threadIdx.x;
  const int lane = t & 63, wave = t >> 6;
  const int lanelo = lane & 15, quad = lane >> 4;
  const int wbase = wave << 5;

  if (bx < TT_BLK) {
    // ---- tiled transpose: fw2 -> w2T, in2f -> in2fT (bf16, [n][k]) ----
    const int mat = bx >> 4, tile = bx & 15;
    const int l = mat >> 1, which = mat & 1;
    const float* src = (which ? in2f : fw2) + (size_t)l * 16384;
    short* dst = (which ? in2fT : w2T) + (size_t)l * 16384;
    const int tk0 = (tile >> 2) << 5, tn0 = (tile & 3) << 5;
    const int tr = t >> 3, tc4 = (t & 7) << 2;
    const float4 v = *(const float4*)(src + (size_t)(tk0 + tr) * 128 + tn0 + tc4);
    sTile[tr][tc4] = f2bf(v.x); sTile[tr][tc4 + 1] = f2bf(v.y);
    sTile[tr][tc4 + 2] = f2bf(v.z); sTile[tr][tc4 + 3] = f2bf(v.w);
    __syncthreads();
    short o[4];
#pragma unroll
    for (int j = 0; j < 4; ++j) o[j] = sTile[tc4 + j][tr];
    uint2 pk;
    pk.x = ((unsigned)(unsigned short)o[0]) | (((unsigned)(unsigned short)o[1]) << 16);
    pk.y = ((unsigned)(unsigned short)o[2]) | (((unsigned)(unsigned short)o[3]) << 16);
    *(uint2*)(dst + (size_t)(tn0 + tr) * 128 + tk0 + tc4) = pk;
    return;
  }
  if (bx < B_PF) {
    // ---- w1T[l][n][k] (k padded 25->32) ----
    const int idx = (bx - B_W1) * 256 + t;
    const int l = idx >> 12, r = idx & 4095, n = r >> 5, k = r & 31;
    w1T[idx] = (k < NG) ? f2bf(fw1[(size_t)l * NG * NF + k * NF + n]) : (short)0;
    return;
  }
  if (bx < B_VA) {
    // ---- W12 = f2o@dw (bf16 [j][i]), b12 = f2ob@dw + db ----
    const int fb = bx - B_PF;
    const int l = fb >> 3, xi = fb & 7;
    const int i = (xi << 4) + lanelo;
    const float* f2o_l = f2o + (size_t)l * 16384;
    const float* dw_l = dw + (size_t)l * 16384;
    short* W12T_l = W12T + (size_t)l * 16384;
    f32x4 c[2] = {{0.f, 0.f, 0.f, 0.f}, {0.f, 0.f, 0.f, 0.f}};
#pragma unroll
    for (int kt = 0; kt < 4; ++kt) {
      const int k0 = kt * 32 + quad * 8;
      const bf16x8 b = pack8(*(const float4*)(f2o_l + (size_t)i * 128 + k0),
                             *(const float4*)(f2o_l + (size_t)i * 128 + k0 + 4));
#pragma unroll
      for (int ct = 0; ct < 2; ++ct) {
        const bf16x8 a = fragT(dw_l, 128, wbase + ct * 16 + lanelo, k0);
        c[ct] = __builtin_amdgcn_mfma_f32_16x16x32_bf16(a, b, c[ct], 0, 0, 0);
      }
    }
#pragma unroll
    for (int ct = 0; ct < 2; ++ct)
#pragma unroll
      for (int reg = 0; reg < 4; ++reg) {
        const int j = wbase + ct * 16 + quad * 4 + reg;
        W12T_l[(size_t)j * 128 + i] = f2bf(c[ct][reg]);
      }
    if (xi == 0 && t < 128) {
      float acc = db[(size_t)l * 128 + t];
      for (int k = 0; k < 128; ++k)
        acc += f2ob[(size_t)l * 128 + k] * dw_l[(size_t)k * 128 + t];
      b12[(size_t)l * 128 + t] = acc;
    }
    return;
  }
  if (bx < B_Y0) {
    // ---- vang[l] = bf16(Gi) @ bf16(aw[l]) (A-frags direct from aw) ----
    const int vb = bx - B_VA;
    const int l = vb >> 8;
    const int row = ((vb & 255) << 4) + lanelo;
    const float* aw_l = aw + (size_t)l * 65536;
    f32x4 c[2] = {{0.f, 0.f, 0.f, 0.f}, {0.f, 0.f, 0.f, 0.f}};
#pragma unroll
    for (int kt = 0; kt < 16; ++kt) {
      const int k0 = kt * 32 + quad * 8;
      const bf16x8 b = pack8(*(const float4*)(Gi + (size_t)row * NGA + k0),
                             *(const float4*)(Gi + (size_t)row * NGA + k0 + 4));
#pragma unroll
      for (int ct = 0; ct < 2; ++ct) {
        const bf16x8 a = fragT(aw_l, 128, wbase + ct * 16 + lanelo, k0);
        c[ct] = __builtin_amdgcn_mfma_f32_16x16x32_bf16(a, b, c[ct], 0, 0, 0);
      }
    }
    float* vrow = vang + ((size_t)l * NB * NA + row) * 128;
#pragma unroll
    for (int ct = 0; ct < 2; ++ct) {
      float4 o = make_float4(c[ct][0], c[ct][1], c[ct][2], c[ct][3]);
      *(float4*)(vrow + wbase + ct * 16 + quad * 4) = o;
    }
    return;
  }
  // ---- y0 = bf16(emb[zn] @ in2f[0]); wave 0 also writes x = emb[zn] ----
  {
    const int row = ((bx - B_Y0) << 4) + lanelo;
    const float* erow = emb + (size_t)zn[row] * ND;
    f32x4 c[2] = {{0.f, 0.f, 0.f, 0.f}, {0.f, 0.f, 0.f, 0.f}};
#pragma unroll
    for (int kt = 0; kt < 4; ++kt) {
      const int k0 = kt * 32 + quad * 8;
      const float4 e0 = *(const float4*)(erow + k0);
      const float4 e1 = *(const float4*)(erow + k0 + 4);
      if (wave == 0) {
        *(float4*)(x + (size_t)row * ND + k0) = e0;
        *(float4*)(x + (size_t)row * ND + k0 + 4) = e1;
      }
      const bf16x8 b = pack8(e0, e1);
#pragma unroll
      for (int ct = 0; ct < 2; ++ct) {
        const bf16x8 a = fragT(in2f, 128, wbase + ct * 16 + lanelo, k0);
        c[ct] = __builtin_amdgcn_mfma_f32_16x16x32_bf16(a, b, c[ct], 0, 0, 0);
      }
    }
#pragma unroll
    for (int ct = 0; ct < 2; ++ct) {
      const int c0 = wbase + ct * 16 + quad * 4;
      uint2 pk; pk.x = pk2bf(c[ct][0], c[ct][1]); pk.y = pk2bf(c[ct][2], c[ct][3]);
      *(uint2*)(yB + (size_t)row * 128 + c0) = pk;
    }
  }
}

// ================= fused CFConv with neighbor compaction ===================
#define HPAD 136
__global__ __launch_bounds__(256) void k_cfconv(
    const float* __restrict__ pos, const int* __restrict__ nbr,
    const int* __restrict__ nmask, const short* __restrict__ yB,
    const short* __restrict__ w1T, const float* __restrict__ b1,
    const short* __restrict__ w2T, const float* __restrict__ b2,
    short* __restrict__ aggB) {
  __shared__ alignas(16) short sH[NN * HPAD];   // aliased as sPart at end
  __shared__ float sR[NN];
  __shared__ float sScale[NN];
  __shared__ int sNbr[NN];
  __shared__ int sNv;

  const int t = threadIdx.x;
  const int ga = blockIdx.x;
  const int b0 = ga & ~(NA - 1);
  const int lane = t & 63;
  const int wave = t >> 6;
  const int lanelo = lane & 15;
  const int quad = lane >> 4;
  const int wbase = wave << 5;     // this wave's 32 f-cols

  bf16x8 bw1[2];
  bf16x8 bw2[8];
#pragma unroll
  for (int ct = 0; ct < 2; ++ct) {
    const int n = wbase + ct * 16 + lanelo;
    bw1[ct] = *(const bf16x8*)(w1T + n * 32 + quad * 8);
#pragma unroll
    for (int kt = 0; kt < 4; ++kt)
      bw2[ct * 4 + kt] = *(const bf16x8*)(w2T + n * 128 + kt * 32 + quad * 8);
  }
  float b2r[2];
#pragma unroll
  for (int ct = 0; ct < 2; ++ct) b2r[ct] = b2[wbase + ct * 16 + lanelo];
  float4 b1v[2];
#pragma unroll
  for (int ct = 0; ct < 2; ++ct)
    b1v[ct] = *(const float4*)(b1 + wbase + ct * 16 + quad * 4);

  // ---- wave 0: distances + ballot compaction ----
  if (t < NN) {
    const int nj = nbr[(size_t)ga * NN + t];
    const float px = pos[(size_t)ga * 3];
    const float py = pos[(size_t)ga * 3 + 1];
    const float pz = pos[(size_t)ga * 3 + 2];
    const float* pj = pos + (size_t)(b0 + nj) * 3;
    const float dx = pj[0] - px, dy = pj[1] - py, dz = pj[2] - pz;
    const float r = sqrtf(dx * dx + dy * dy + dz * dz + 1e-12f);
    const bool valid = (r <= 5.0f) && (nmask[(size_t)ga * NN + t] != 0);
    sR[t] = 1.0f; sScale[t] = 0.0f; sNbr[t] = 0;
    const unsigned long long m = __ballot(valid);
    const int pos_c = __popcll(m & ((1ull << lane) - 1ull));
    if (valid) { sNbr[pos_c] = nj; sR[pos_c] = r; sScale[pos_c] = 1.0f; }
    if (lane == 0) sNv = (int)__popcll(m);
  }
  __syncthreads();

  const int ntiles = (sNv + 15) >> 4;

  const float step = 3.8f / 24.0f;
  const float coef = -0.5f / (step * step);

  // ---- phase 1: h = ssp(f @ w1 + b1) for compacted tiles ----
  for (int jt = 0; jt < ntiles; ++jt) {
    const int j = jt * 16 + lanelo;
    const float r = sR[j];
    bf16x8 gb;
    {
      float e[8];
#pragma unroll
      for (int i = 0; i < 8; ++i) {
        const int g = quad * 8 + i;
        const float d = r - (1.2f + step * (float)g);
        e[i] = (g < NG) ? __expf(coef * d * d) : 0.0f;
      }
      unsigned* gp = (unsigned*)&gb;
      gp[0] = pk2bf(e[0], e[1]); gp[1] = pk2bf(e[2], e[3]);
      gp[2] = pk2bf(e[4], e[5]); gp[3] = pk2bf(e[6], e[7]);
    }
#pragma unroll
    for (int ct = 0; ct < 2; ++ct) {
      f32x4 c = {0.f, 0.f, 0.f, 0.f};
      c = __builtin_amdgcn_mfma_f32_16x16x32_bf16(bw1[ct], gb, c, 0, 0, 0);
      const int f0 = wbase + ct * 16 + quad * 4;
      uint2 pk;
      pk.x = pk2bf(sspf(c[0] + b1v[ct].x), sspf(c[1] + b1v[ct].y));
      pk.y = pk2bf(sspf(c[2] + b1v[ct].z), sspf(c[3] + b1v[ct].w));
      *(uint2*)(sH + j * HPAD + f0) = pk;
    }
  }
  __syncthreads();

  // ---- phase 2: W = h @ w2 (+b2 via C-init); consume global bf16 y ----
  float pagg[2] = {0.f, 0.f};
  for (int rt = 0; rt < ntiles; ++rt) {
    f32x4 acc[2];
    acc[0] = (f32x4){b2r[0], b2r[0], b2r[0], b2r[0]};
    acc[1] = (f32x4){b2r[1], b2r[1], b2r[1], b2r[1]};
#pragma unroll
    for (int kt = 0; kt < 4; ++kt) {
      const bf16x8 ah = *(const bf16x8*)(sH + (rt * 16 + lanelo) * HPAD + kt * 32 + quad * 8);
#pragma unroll
      for (int ct = 0; ct < 2; ++ct)
        acc[ct] = __builtin_amdgcn_mfma_f32_16x16x32_bf16(ah, bw2[ct * 4 + kt], acc[ct], 0, 0, 0);
    }
#pragma unroll
    for (int reg = 0; reg < 4; ++reg) {
      const int j = rt * 16 + quad * 4 + reg;
      const float sc = sScale[j];
      const unsigned short* yr =
          (const unsigned short*)(yB + (size_t)(b0 + sNbr[j]) * NF) + wbase + lanelo;
#pragma unroll
      for (int ct = 0; ct < 2; ++ct)
        pagg[ct] = fmaf(sc * acc[ct][reg], bf2f(yr[ct * 16]), pagg[ct]);
    }
  }

  __syncthreads();
  float* sPart = (float*)sH;
#pragma unroll
  for (int ct = 0; ct < 2; ++ct)
    sPart[quad * NF + wbase + ct * 16 + lanelo] = pagg[ct];
  __syncthreads();
  if (t < NF)
    aggB[(size_t)ga * NF + t] =
        f2bf(sPart[t] + sPart[NF + t] + sPart[2 * NF + t] + sPart[3 * NF + t]);
}

// ================= per-layer update (fused W12, 2 GEMMs) ===================
#define TPAD 136
__global__ __launch_bounds__(256) void k_upd(
    float* __restrict__ x, const short* __restrict__ aggB,
    const float* __restrict__ vang,
    const short* __restrict__ W12Tl, const float* __restrict__ b12l,
    const short* __restrict__ in2fT, short* __restrict__ yB) {
  __shared__ alignas(16) short sT[16 * TPAD];
  const int t = threadIdx.x;
  const int lane = t & 63, wave = t >> 6;
  const int lanelo = lane & 15, quad = lane >> 4;
  const int wbase = wave << 5;
  const int row = (blockIdx.x << 4) + lanelo;

  f32x4 c2[2] = {{0.f, 0.f, 0.f, 0.f}, {0.f, 0.f, 0.f, 0.f}};
#pragma unroll
  for (int kt = 0; kt < 4; ++kt) {
    const bf16x8 b = *(const bf16x8*)(aggB + (size_t)row * 128 + kt * 32 + quad * 8);
#pragma unroll
    for (int ct = 0; ct < 2; ++ct) {
      const bf16x8 a = *(const bf16x8*)(W12Tl + (wbase + ct * 16 + lanelo) * 128 + kt * 32 + quad * 8);
      c2[ct] = __builtin_amdgcn_mfma_f32_16x16x32_bf16(a, b, c2[ct], 0, 0, 0);
    }
  }

#pragma unroll
  for (int ct = 0; ct < 2; ++ct) {
    const int c0 = wbase + ct * 16 + quad * 4;
    const float4 dv = *(const float4*)(b12l + c0);
    const float4 vv = *(const float4*)(vang + (size_t)row * 128 + c0);
    float* xp = x + (size_t)row * 128 + c0;
    const float4 xv = *(const float4*)xp;
    float4 xo;
    xo.x = xv.x + sspf(c2[ct][0] + vv.x + dv.x);
    xo.y = xv.y + sspf(c2[ct][1] + vv.y + dv.y);
    xo.z = xv.z + sspf(c2[ct][2] + vv.z + dv.z);
    xo.w = xv.w + sspf(c2[ct][3] + vv.w + dv.w);
    *(float4*)xp = xo;
    if (in2fT != nullptr) {
      uint2 pk; pk.x = pk2bf(xo.x, xo.y); pk.y = pk2bf(xo.z, xo.w);
      *(uint2*)(sT + lanelo * TPAD + c0) = pk;
    }
  }
  if (in2fT == nullptr) return;
  __syncthreads();

  f32x4 c3[2] = {{0.f, 0.f, 0.f, 0.f}, {0.f, 0.f, 0.f, 0.f}};
#pragma unroll
  for (int kt = 0; kt < 4; ++kt) {
    const bf16x8 b = *(const bf16x8*)(sT + lanelo * TPAD + kt * 32 + quad * 8);
#pragma unroll
    for (int ct = 0; ct < 2; ++ct) {
      const bf16x8 a = *(const bf16x8*)(in2fT + (wbase + ct * 16 + lanelo) * 128 + kt * 32 + quad * 8);
      c3[ct] = __builtin_amdgcn_mfma_f32_16x16x32_bf16(a, b, c3[ct], 0, 0, 0);
    }
  }
#pragma unroll
  for (int ct = 0; ct < 2; ++ct) {
    const int c0 = wbase + ct * 16 + quad * 4;
    uint2 pk; pk.x = pk2bf(c3[ct][0], c3[ct][1]); pk.y = pk2bf(c3[ct][2], c3[ct][3]);
    *(uint2*)(yB + (size_t)row * 128 + c0) = pk;
  }
}

extern "C" void kernel_launch(void* const* d_in, const int* in_sizes, int n_in,
                              void* d_out, int out_size, void* d_ws, size_t ws_size,
                              hipStream_t stream) {
  (void)in_sizes; (void)n_in; (void)out_size; (void)ws_size;
  const int* zn = (const int*)d_in[0];
  const float* pos = (const float*)d_in[1];
  const int* nbr = (const int*)d_in[2];
  const int* nmask = (const int*)d_in[3];
  const float* Gi = (const float*)d_in[4];
  const float* emb = (const float*)d_in[5];
  const float* fw1 = (const float*)d_in[6];
  const float* fb1 = (const float*)d_in[7];
  const float* fw2 = (const float*)d_in[8];
  const float* fb2 = (const float*)d_in[9];
  const float* in2f = (const float*)d_in[10];
  const float* f2o = (const float*)d_in[11];
  const float* f2ob = (const float*)d_in[12];
  const float* dwp = (const float*)d_in[13];
  const float* dbp = (const float*)d_in[14];
  const float* awp = (const float*)d_in[15];

  float* x = (float*)d_out;                            // [B,A,D] fp32
  float* vang = (float*)d_ws;                          // [3][B*A][128] fp32
  float* b12 = vang + (size_t)3 * NB * NA * ND;        // [3][128] fp32
  short* yB = (short*)(b12 + 3 * 128);                 // [B,A,F] bf16
  short* aggB = yB + (size_t)NB * NA * NF;             // [B,A,F] bf16
  short* w1T = aggB + (size_t)NB * NA * NF;            // [3][128][32]
  short* w2T = w1T + NW1;                              // [3][128][128]
  short* in2fT = w2T + NSQ;                            // [3][128][128]
  short* W12T = in2fT + NSQ;                           // [3][128][128]

  k_prep<<<PREP_BLK, 256, 0, stream>>>(
      fw1, fw2, in2f, awp, f2o, f2ob, dwp, dbp, emb, Gi, zn,
      w1T, w2T, in2fT, W12T, b12, vang, x, yB);
  for (int l = 0; l < 3; ++l) {
    k_cfconv<<<NB * NA, 256, 0, stream>>>(pos, nbr, nmask, yB,
        w1T + (size_t)l * 128 * 32, fb1 + (size_t)l * NF,
        w2T + (size_t)l * 128 * 128, fb2 + (size_t)l * NF, aggB);
    k_upd<<<NB * NA / 16, 256, 0, stream>>>(x, aggB,
        vang + (size_t)l * NB * NA * ND,
        W12T + (size_t)l * 16384, b12 + (size_t)l * 128,
        (l < 2) ? (in2fT + (size_t)(l + 1) * 16384) : nullptr, yB);
  }
}

// Round 13
// 212.562 us; speedup vs baseline: 1.4257x; 1.0033x over previous
//
#include <hip/hip_runtime.h>
#include <math.h>

#define NB 8
#define NA 512
#define NN 64
#define ND 128
#define NF 128
#define NG 25
#define NGA 512

typedef __attribute__((ext_vector_type(8))) short bf16x8;
typedef __attribute__((ext_vector_type(4))) float f32x4;

__device__ __forceinline__ float sspf(float v) {
  return fmaxf(v, 0.0f) + __logf(1.0f + __expf(-fabsf(v))) - 0.6931471805599453f;
}

__device__ __forceinline__ short f2bf(float x) {
  union { float f; unsigned u; } v; v.f = x;
  unsigned r = v.u + 0x7fffu + ((v.u >> 16) & 1u);   // RNE
  return (short)(r >> 16);
}

#if defined(__has_builtin)
#if __has_builtin(__builtin_amdgcn_cvt_pk_bf16_f32)
#define HAS_PKBF 1
#endif
#endif

__device__ __forceinline__ unsigned pk2bf(float a, float b) {
#ifdef HAS_PKBF
  typedef __attribute__((ext_vector_type(2))) __bf16 v2bf;
  union { v2bf v; unsigned u; } c;
  c.v = __builtin_amdgcn_cvt_pk_bf16_f32(a, b);
  return c.u;
#else
  union { float f; unsigned u; } x, y; x.f = a; y.f = b;
  const unsigned ra = (x.u + 0x7fffu + ((x.u >> 16) & 1u)) >> 16;
  const unsigned rb = (y.u + 0x7fffu + ((y.u >> 16) & 1u)) & 0xffff0000u;
  return ra | rb;
#endif
}

__device__ __forceinline__ float bf2f(unsigned short us) {
  union { unsigned u; float f; } v; v.u = ((unsigned)us) << 16; return v.f;
}

__device__ __forceinline__ bf16x8 pack8(float4 a, float4 b) {
  bf16x8 r;
  unsigned* p = (unsigned*)&r;
  p[0] = pk2bf(a.x, a.y); p[1] = pk2bf(a.z, a.w);
  p[2] = pk2bf(b.x, b.y); p[3] = pk2bf(b.z, b.w);
  return r;
}

// W^T-style fragment built from row-major M[k][n]: elem i = bf16(M[k0q+i][n])
__device__ __forceinline__ bf16x8 fragT(const float* __restrict__ M, int ldn,
                                        int n, int k0q) {
  float e[8];
#pragma unroll
  for (int i = 0; i < 8; ++i) e[i] = M[(size_t)(k0q + i) * ldn + n];
  bf16x8 r; unsigned* p = (unsigned*)&r;
  p[0] = pk2bf(e[0], e[1]); p[1] = pk2bf(e[2], e[3]);
  p[2] = pk2bf(e[4], e[5]); p[3] = pk2bf(e[6], e[7]);
  return r;
}

#define NW1 (3 * 128 * 32)      // 12288
#define NSQ (3 * 128 * 128)     // 49152
// k_prep grid layout (all blocks independent):
#define TT_BLK 96               // 6 square mats x 16 (32x32) tiles
#define W1_BLK 48               // w1T scalar transpose
#define PF_BLK 24               // W12 fuse
#define VA_BLK 768              // vang direct
#define Y0_BLK 256              // y0 + x init
#define B_W1 (TT_BLK)
#define B_PF (B_W1 + W1_BLK)
#define B_VA (B_PF + PF_BLK)
#define B_Y0 (B_VA + VA_BLK)
#define PREP_BLK (B_Y0 + Y0_BLK)   // 1192

// ================= single prep kernel: no inter-block dependencies =========
__global__ __launch_bounds__(256) void k_prep(
    const float* __restrict__ fw1, const float* __restrict__ fw2,
    const float* __restrict__ in2f, const float* __restrict__ aw,
    const float* __restrict__ f2o, const float* __restrict__ f2ob,
    const float* __restrict__ dw, const float* __restrict__ db,
    const float* __restrict__ emb, const float* __restrict__ Gi,
    const int* __restrict__ zn,
    short* __restrict__ w1T, short* __restrict__ w2T,
    short* __restrict__ in2fT, short* __restrict__ W12T,
    float* __restrict__ b12, short* __restrict__ vangB,
    float* __restrict__ x, short* __restrict__ yB) {
  __shared__ short sTile[32][33];
  const int bx = blockIdx.x;
  const int t = threadIdx.x;
  const int lane = t & 63, wave = t >> 6;
  const int lanelo = lane & 15, quad = lane >> 4;
  const int wbase = wave << 5;

  if (bx < TT_BLK) {
    // ---- tiled transpose: fw2 -> w2T, in2f -> in2fT (bf16, [n][k]) ----
    const int mat = bx >> 4, tile = bx & 15;
    const int l = mat >> 1, which = mat & 1;
    const float* src = (which ? in2f : fw2) + (size_t)l * 16384;
    short* dst = (which ? in2fT : w2T) + (size_t)l * 16384;
    const int tk0 = (tile >> 2) << 5, tn0 = (tile & 3) << 5;
    const int tr = t >> 3, tc4 = (t & 7) << 2;
    const float4 v = *(const float4*)(src + (size_t)(tk0 + tr) * 128 + tn0 + tc4);
    sTile[tr][tc4] = f2bf(v.x); sTile[tr][tc4 + 1] = f2bf(v.y);
    sTile[tr][tc4 + 2] = f2bf(v.z); sTile[tr][tc4 + 3] = f2bf(v.w);
    __syncthreads();
    short o[4];
#pragma unroll
    for (int j = 0; j < 4; ++j) o[j] = sTile[tc4 + j][tr];
    uint2 pk;
    pk.x = ((unsigned)(unsigned short)o[0]) | (((unsigned)(unsigned short)o[1]) << 16);
    pk.y = ((unsigned)(unsigned short)o[2]) | (((unsigned)(unsigned short)o[3]) << 16);
    *(uint2*)(dst + (size_t)(tn0 + tr) * 128 + tk0 + tc4) = pk;
    return;
  }
  if (bx < B_PF) {
    // ---- w1T[l][n][k] (k padded 25->32) ----
    const int idx = (bx - B_W1) * 256 + t;
    const int l = idx >> 12, r = idx & 4095, n = r >> 5, k = r & 31;
    w1T[idx] = (k < NG) ? f2bf(fw1[(size_t)l * NG * NF + k * NF + n]) : (short)0;
    return;
  }
  if (bx < B_VA) {
    // ---- W12 = f2o@dw (bf16 [j][i]), b12 = f2ob@dw + db ----
    const int fb = bx - B_PF;
    const int l = fb >> 3, xi = fb & 7;
    const int i = (xi << 4) + lanelo;
    const float* f2o_l = f2o + (size_t)l * 16384;
    const float* dw_l = dw + (size_t)l * 16384;
    short* W12T_l = W12T + (size_t)l * 16384;
    f32x4 c[2] = {{0.f, 0.f, 0.f, 0.f}, {0.f, 0.f, 0.f, 0.f}};
#pragma unroll
    for (int kt = 0; kt < 4; ++kt) {
      const int k0 = kt * 32 + quad * 8;
      const bf16x8 b = pack8(*(const float4*)(f2o_l + (size_t)i * 128 + k0),
                             *(const float4*)(f2o_l + (size_t)i * 128 + k0 + 4));
#pragma unroll
      for (int ct = 0; ct < 2; ++ct) {
        const bf16x8 a = fragT(dw_l, 128, wbase + ct * 16 + lanelo, k0);
        c[ct] = __builtin_amdgcn_mfma_f32_16x16x32_bf16(a, b, c[ct], 0, 0, 0);
      }
    }
#pragma unroll
    for (int ct = 0; ct < 2; ++ct)
#pragma unroll
      for (int reg = 0; reg < 4; ++reg) {
        const int j = wbase + ct * 16 + quad * 4 + reg;
        W12T_l[(size_t)j * 128 + i] = f2bf(c[ct][reg]);
      }
    if (xi == 0 && t < 128) {
      float acc = db[(size_t)l * 128 + t];
      for (int k = 0; k < 128; ++k)
        acc += f2ob[(size_t)l * 128 + k] * dw_l[(size_t)k * 128 + t];
      b12[(size_t)l * 128 + t] = acc;
    }
    return;
  }
  if (bx < B_Y0) {
    // ---- vangB[l] = bf16(bf16(Gi) @ bf16(aw[l])) ----
    const int vb = bx - B_VA;
    const int l = vb >> 8;
    const int row = ((vb & 255) << 4) + lanelo;
    const float* aw_l = aw + (size_t)l * 65536;
    f32x4 c[2] = {{0.f, 0.f, 0.f, 0.f}, {0.f, 0.f, 0.f, 0.f}};
#pragma unroll
    for (int kt = 0; kt < 16; ++kt) {
      const int k0 = kt * 32 + quad * 8;
      const bf16x8 b = pack8(*(const float4*)(Gi + (size_t)row * NGA + k0),
                             *(const float4*)(Gi + (size_t)row * NGA + k0 + 4));
#pragma unroll
      for (int ct = 0; ct < 2; ++ct) {
        const bf16x8 a = fragT(aw_l, 128, wbase + ct * 16 + lanelo, k0);
        c[ct] = __builtin_amdgcn_mfma_f32_16x16x32_bf16(a, b, c[ct], 0, 0, 0);
      }
    }
    short* vrow = vangB + ((size_t)l * NB * NA + row) * 128;
#pragma unroll
    for (int ct = 0; ct < 2; ++ct) {
      uint2 pk; pk.x = pk2bf(c[ct][0], c[ct][1]); pk.y = pk2bf(c[ct][2], c[ct][3]);
      *(uint2*)(vrow + wbase + ct * 16 + quad * 4) = pk;
    }
    return;
  }
  // ---- y0 = bf16(emb[zn] @ in2f[0]); wave 0 also writes x = emb[zn] ----
  {
    const int row = ((bx - B_Y0) << 4) + lanelo;
    const float* erow = emb + (size_t)zn[row] * ND;
    f32x4 c[2] = {{0.f, 0.f, 0.f, 0.f}, {0.f, 0.f, 0.f, 0.f}};
#pragma unroll
    for (int kt = 0; kt < 4; ++kt) {
      const int k0 = kt * 32 + quad * 8;
      const float4 e0 = *(const float4*)(erow + k0);
      const float4 e1 = *(const float4*)(erow + k0 + 4);
      if (wave == 0) {
        *(float4*)(x + (size_t)row * ND + k0) = e0;
        *(float4*)(x + (size_t)row * ND + k0 + 4) = e1;
      }
      const bf16x8 b = pack8(e0, e1);
#pragma unroll
      for (int ct = 0; ct < 2; ++ct) {
        const bf16x8 a = fragT(in2f, 128, wbase + ct * 16 + lanelo, k0);
        c[ct] = __builtin_amdgcn_mfma_f32_16x16x32_bf16(a, b, c[ct], 0, 0, 0);
      }
    }
#pragma unroll
    for (int ct = 0; ct < 2; ++ct) {
      const int c0 = wbase + ct * 16 + quad * 4;
      uint2 pk; pk.x = pk2bf(c[ct][0], c[ct][1]); pk.y = pk2bf(c[ct][2], c[ct][3]);
      *(uint2*)(yB + (size_t)row * 128 + c0) = pk;
    }
  }
}

// ================= fused CFConv with neighbor compaction ===================
// Compacted valid neighbors (avg ~10/64) -> 16-row tiles (typ. 1).
// phase1: wave w owns f-cols [w*32,+32), loops j-tiles; gauss frag in-register.
// phase2: same f-cols; j lives in quad dim -> in-wave shuffle reduction (no LDS).
#define HPAD 136
__global__ __launch_bounds__(256) void k_cfconv(
    const float* __restrict__ pos, const int* __restrict__ nbr,
    const int* __restrict__ nmask, const short* __restrict__ yB,
    const short* __restrict__ w1T, const float* __restrict__ b1,
    const short* __restrict__ w2T, const float* __restrict__ b2,
    short* __restrict__ aggB) {
  __shared__ alignas(16) short sH[NN * HPAD];
  __shared__ float sR[NN];
  __shared__ float sScale[NN];
  __shared__ int sNbr[NN];
  __shared__ int sNv;

  const int t = threadIdx.x;
  const int ga = blockIdx.x;
  const int b0 = ga & ~(NA - 1);
  const int lane = t & 63;
  const int wave = t >> 6;
  const int lanelo = lane & 15;
  const int quad = lane >> 4;
  const int wbase = wave << 5;     // this wave's 32 f-cols

  bf16x8 bw1[2];
  bf16x8 bw2[8];
#pragma unroll
  for (int ct = 0; ct < 2; ++ct) {
    const int n = wbase + ct * 16 + lanelo;
    bw1[ct] = *(const bf16x8*)(w1T + n * 32 + quad * 8);
#pragma unroll
    for (int kt = 0; kt < 4; ++kt)
      bw2[ct * 4 + kt] = *(const bf16x8*)(w2T + n * 128 + kt * 32 + quad * 8);
  }
  float b2r[2];
#pragma unroll
  for (int ct = 0; ct < 2; ++ct) b2r[ct] = b2[wbase + ct * 16 + lanelo];
  float4 b1v[2];
#pragma unroll
  for (int ct = 0; ct < 2; ++ct)
    b1v[ct] = *(const float4*)(b1 + wbase + ct * 16 + quad * 4);

  // ---- wave 0: distances + ballot compaction ----
  if (t < NN) {
    const int nj = nbr[(size_t)ga * NN + t];
    const float px = pos[(size_t)ga * 3];
    const float py = pos[(size_t)ga * 3 + 1];
    const float pz = pos[(size_t)ga * 3 + 2];
    const float* pj = pos + (size_t)(b0 + nj) * 3;
    const float dx = pj[0] - px, dy = pj[1] - py, dz = pj[2] - pz;
    const float r = sqrtf(dx * dx + dy * dy + dz * dz + 1e-12f);
    const bool valid = (r <= 5.0f) && (nmask[(size_t)ga * NN + t] != 0);
    sR[t] = 1.0f; sScale[t] = 0.0f; sNbr[t] = 0;
    const unsigned long long m = __ballot(valid);
    const int pos_c = __popcll(m & ((1ull << lane) - 1ull));
    if (valid) { sNbr[pos_c] = nj; sR[pos_c] = r; sScale[pos_c] = 1.0f; }
    if (lane == 0) sNv = (int)__popcll(m);
  }
  __syncthreads();

  const int ntiles = (sNv + 15) >> 4;

  const float step = 3.8f / 24.0f;
  const float coef = -0.5f / (step * step);

  // ---- phase 1: h = ssp(f @ w1 + b1) for compacted tiles ----
  for (int jt = 0; jt < ntiles; ++jt) {
    const int j = jt * 16 + lanelo;
    const float r = sR[j];
    bf16x8 gb;
    {
      float e[8];
#pragma unroll
      for (int i = 0; i < 8; ++i) {
        const int g = quad * 8 + i;
        const float d = r - (1.2f + step * (float)g);
        e[i] = (g < NG) ? __expf(coef * d * d) : 0.0f;
      }
      unsigned* gp = (unsigned*)&gb;
      gp[0] = pk2bf(e[0], e[1]); gp[1] = pk2bf(e[2], e[3]);
      gp[2] = pk2bf(e[4], e[5]); gp[3] = pk2bf(e[6], e[7]);
    }
#pragma unroll
    for (int ct = 0; ct < 2; ++ct) {
      f32x4 c = {0.f, 0.f, 0.f, 0.f};
      c = __builtin_amdgcn_mfma_f32_16x16x32_bf16(bw1[ct], gb, c, 0, 0, 0);
      const int f0 = wbase + ct * 16 + quad * 4;
      uint2 pk;
      pk.x = pk2bf(sspf(c[0] + b1v[ct].x), sspf(c[1] + b1v[ct].y));
      pk.y = pk2bf(sspf(c[2] + b1v[ct].z), sspf(c[3] + b1v[ct].w));
      *(uint2*)(sH + j * HPAD + f0) = pk;
    }
  }
  __syncthreads();

  // ---- phase 2: W = h @ w2 (+b2 via C-init); consume global bf16 y ----
  float pagg[2] = {0.f, 0.f};
  for (int rt = 0; rt < ntiles; ++rt) {
    f32x4 acc[2];
    acc[0] = (f32x4){b2r[0], b2r[0], b2r[0], b2r[0]};
    acc[1] = (f32x4){b2r[1], b2r[1], b2r[1], b2r[1]};
#pragma unroll
    for (int kt = 0; kt < 4; ++kt) {
      const bf16x8 ah = *(const bf16x8*)(sH + (rt * 16 + lanelo) * HPAD + kt * 32 + quad * 8);
#pragma unroll
      for (int ct = 0; ct < 2; ++ct)
        acc[ct] = __builtin_amdgcn_mfma_f32_16x16x32_bf16(ah, bw2[ct * 4 + kt], acc[ct], 0, 0, 0);
    }
#pragma unroll
    for (int reg = 0; reg < 4; ++reg) {
      const int j = rt * 16 + quad * 4 + reg;
      const float sc = sScale[j];
      const unsigned short* yr =
          (const unsigned short*)(yB + (size_t)(b0 + sNbr[j]) * NF) + wbase + lanelo;
#pragma unroll
      for (int ct = 0; ct < 2; ++ct)
        pagg[ct] = fmaf(sc * acc[ct][reg], bf2f(yr[ct * 16]), pagg[ct]);
    }
  }

  // ---- in-wave reduction over quads (j dim): 2 shuffles, no barrier ----
#pragma unroll
  for (int ct = 0; ct < 2; ++ct) {
    pagg[ct] += __shfl_xor(pagg[ct], 16, 64);
    pagg[ct] += __shfl_xor(pagg[ct], 32, 64);
  }
  if (quad == 0) {
    aggB[(size_t)ga * NF + wbase + lanelo] = f2bf(pagg[0]);
    aggB[(size_t)ga * NF + wbase + 16 + lanelo] = f2bf(pagg[1]);
  }
}

// ================= per-layer update (fused W12, 2 GEMMs) ===================
#define TPAD 136
__global__ __launch_bounds__(256) void k_upd(
    float* __restrict__ x, const short* __restrict__ aggB,
    const short* __restrict__ vangB,
    const short* __restrict__ W12Tl, const float* __restrict__ b12l,
    const short* __restrict__ in2fT, short* __restrict__ yB) {
  __shared__ alignas(16) short sT[16 * TPAD];
  const int t = threadIdx.x;
  const int lane = t & 63, wave = t >> 6;
  const int lanelo = lane & 15, quad = lane >> 4;
  const int wbase = wave << 5;
  const int row = (blockIdx.x << 4) + lanelo;

  f32x4 c2[2] = {{0.f, 0.f, 0.f, 0.f}, {0.f, 0.f, 0.f, 0.f}};
#pragma unroll
  for (int kt = 0; kt < 4; ++kt) {
    const bf16x8 b = *(const bf16x8*)(aggB + (size_t)row * 128 + kt * 32 + quad * 8);
#pragma unroll
    for (int ct = 0; ct < 2; ++ct) {
      const bf16x8 a = *(const bf16x8*)(W12Tl + (wbase + ct * 16 + lanelo) * 128 + kt * 32 + quad * 8);
      c2[ct] = __builtin_amdgcn_mfma_f32_16x16x32_bf16(a, b, c2[ct], 0, 0, 0);
    }
  }

#pragma unroll
  for (int ct = 0; ct < 2; ++ct) {
    const int c0 = wbase + ct * 16 + quad * 4;
    const float4 dv = *(const float4*)(b12l + c0);
    const unsigned short* vp = (const unsigned short*)(vangB + (size_t)row * 128 + c0);
    float* xp = x + (size_t)row * 128 + c0;
    const float4 xv = *(const float4*)xp;
    float4 xo;
    xo.x = xv.x + sspf(c2[ct][0] + bf2f(vp[0]) + dv.x);
    xo.y = xv.y + sspf(c2[ct][1] + bf2f(vp[1]) + dv.y);
    xo.z = xv.z + sspf(c2[ct][2] + bf2f(vp[2]) + dv.z);
    xo.w = xv.w + sspf(c2[ct][3] + bf2f(vp[3]) + dv.w);
    *(float4*)xp = xo;
    if (in2fT != nullptr) {
      uint2 pk; pk.x = pk2bf(xo.x, xo.y); pk.y = pk2bf(xo.z, xo.w);
      *(uint2*)(sT + lanelo * TPAD + c0) = pk;
    }
  }
  if (in2fT == nullptr) return;
  __syncthreads();

  f32x4 c3[2] = {{0.f, 0.f, 0.f, 0.f}, {0.f, 0.f, 0.f, 0.f}};
#pragma unroll
  for (int kt = 0; kt < 4; ++kt) {
    const bf16x8 b = *(const bf16x8*)(sT + lanelo * TPAD + kt * 32 + quad * 8);
#pragma unroll
    for (int ct = 0; ct < 2; ++ct) {
      const bf16x8 a = *(const bf16x8*)(in2fT + (wbase + ct * 16 + lanelo) * 128 + kt * 32 + quad * 8);
      c3[ct] = __builtin_amdgcn_mfma_f32_16x16x32_bf16(a, b, c3[ct], 0, 0, 0);
    }
  }
#pragma unroll
  for (int ct = 0; ct < 2; ++ct) {
    const int c0 = wbase + ct * 16 + quad * 4;
    uint2 pk; pk.x = pk2bf(c3[ct][0], c3[ct][1]); pk.y = pk2bf(c3[ct][2], c3[ct][3]);
    *(uint2*)(yB + (size_t)row * 128 + c0) = pk;
  }
}

extern "C" void kernel_launch(void* const* d_in, const int* in_sizes, int n_in,
                              void* d_out, int out_size, void* d_ws, size_t ws_size,
                              hipStream_t stream) {
  (void)in_sizes; (void)n_in; (void)out_size; (void)ws_size;
  const int* zn = (const int*)d_in[0];
  const float* pos = (const float*)d_in[1];
  const int* nbr = (const int*)d_in[2];
  const int* nmask = (const int*)d_in[3];
  const float* Gi = (const float*)d_in[4];
  const float* emb = (const float*)d_in[5];
  const float* fw1 = (const float*)d_in[6];
  const float* fb1 = (const float*)d_in[7];
  const float* fw2 = (const float*)d_in[8];
  const float* fb2 = (const float*)d_in[9];
  const float* in2f = (const float*)d_in[10];
  const float* f2o = (const float*)d_in[11];
  const float* f2ob = (const float*)d_in[12];
  const float* dwp = (const float*)d_in[13];
  const float* dbp = (const float*)d_in[14];
  const float* awp = (const float*)d_in[15];

  float* x = (float*)d_out;                            // [B,A,D] fp32
  float* b12 = (float*)d_ws;                           // [3][128] fp32
  short* vangB = (short*)(b12 + 3 * 128);              // [3][B*A][128] bf16
  short* yB = vangB + (size_t)3 * NB * NA * ND;        // [B,A,F] bf16
  short* aggB = yB + (size_t)NB * NA * NF;             // [B,A,F] bf16
  short* w1T = aggB + (size_t)NB * NA * NF;            // [3][128][32]
  short* w2T = w1T + NW1;                              // [3][128][128]
  short* in2fT = w2T + NSQ;                            // [3][128][128]
  short* W12T = in2fT + NSQ;                           // [3][128][128]

  k_prep<<<PREP_BLK, 256, 0, stream>>>(
      fw1, fw2, in2f, awp, f2o, f2ob, dwp, dbp, emb, Gi, zn,
      w1T, w2T, in2fT, W12T, b12, vangB, x, yB);
  for (int l = 0; l < 3; ++l) {
    k_cfconv<<<NB * NA, 256, 0, stream>>>(pos, nbr, nmask, yB,
        w1T + (size_t)l * 128 * 32, fb1 + (size_t)l * NF,
        w2T + (size_t)l * 128 * 128, fb2 + (size_t)l * NF, aggB);
    k_upd<<<NB * NA / 16, 256, 0, stream>>>(x, aggB,
        vangB + (size_t)l * NB * NA * ND,
        W12T + (size_t)l * 16384, b12 + (size_t)l * 128,
        (l < 2) ? (in2fT + (size_t)(l + 1) * 16384) : nullptr, yB);
  }
}